// Round 6
// baseline (290.237 us; speedup 1.0000x reference)
//
#include <hip/hip_runtime.h>

typedef unsigned short u16;
typedef __bf16 bf16x8 __attribute__((ext_vector_type(8)));
typedef unsigned short u16x8v __attribute__((ext_vector_type(8)));
typedef unsigned short u16x4v __attribute__((ext_vector_type(4)));
typedef float f32x4 __attribute__((ext_vector_type(4)));

#define SEQ 2048
#define NH 16
#define HD 64
#define DIMM 1024

__device__ __forceinline__ u16 f2bf(float f) {
  unsigned u = __builtin_bit_cast(unsigned, f);
  u += 0x7fffu + ((u >> 16) & 1u);
  return (u16)(u >> 16);
}
__device__ __forceinline__ float bf2f(u16 b) {
  return __builtin_bit_cast(float, ((unsigned)b) << 16);
}

// ---------- split-convert x (f32 -> bf16 hi + bf16 lo) ----------
__global__ void conv_x_split(const float* __restrict__ x, u16* __restrict__ oh,
                             u16* __restrict__ ol) {
  size_t i = (size_t)blockIdx.x * 256 + threadIdx.x;
  f32x4 v = *(const f32x4*)(x + i * 4);
  u16x4v h, l;
#pragma unroll
  for (int j = 0; j < 4; ++j) {
    h[j] = f2bf(v[j]);
    l[j] = f2bf(v[j] - bf2f(h[j]));
  }
  *(u16x4v*)(oh + i * 4) = h;
  *(u16x4v*)(ol + i * 4) = l;
}

// ---------- transpose + split: W[K][N] f32 -> Wt{h,l}[N][K] bf16 ----------
__global__ void conv_wT_split(const float* __restrict__ W, u16* __restrict__ Wth,
                              u16* __restrict__ Wtl, int Kd, int Nd) {
  __shared__ float t[32][33];
  int n0 = blockIdx.x * 32, k0 = blockIdx.y * 32;
  int c = threadIdx.x & 31, r8 = threadIdx.x >> 5;
#pragma unroll
  for (int rr = 0; rr < 32; rr += 8)
    t[r8 + rr][c] = W[(size_t)(k0 + r8 + rr) * Nd + n0 + c];
  __syncthreads();
#pragma unroll
  for (int rr = 0; rr < 32; rr += 8) {
    float v = t[c][r8 + rr];
    u16 h = f2bf(v);
    Wth[(size_t)(n0 + r8 + rr) * Kd + k0 + c] = h;
    Wtl[(size_t)(n0 + r8 + rr) * Kd + k0 + c] = f2bf(v - bf2f(h));
  }
}

// ---------- 3-term split GEMM: C = Ah@Bh + Ah@Bl + Al@Bh (fp32-accurate) ----
// A{h,l}[M][K] bf16 row-major, Bt{h,l}[N][K] bf16 row-major (B transposed).
// MODE 0: Q  -> rope in fp32, write bf16 C0 [b,h,s,d]
// MODE 1: KV -> cols<1024: rope, write K to C0; cols>=1024: write V to C1
// MODE 2: write f32 to CF[M][N]
template <int MODE>
__global__ void __launch_bounds__(256, 2)
gemm3(const u16* __restrict__ Ah, const u16* __restrict__ Al,
      const u16* __restrict__ Bth, const u16* __restrict__ Btl,
      u16* __restrict__ C0, u16* __restrict__ C1, float* __restrict__ CF,
      int M, int N, int K) {
  __shared__ u16 AsH[128][72];
  __shared__ u16 AsL[128][72];
  __shared__ u16 BsH[128][72];
  __shared__ u16 BsL[128][72];
  const int tid = threadIdx.x;
  const int lane = tid & 63, wave = tid >> 6;
  const int wr = wave >> 1, wc = wave & 1;
  const int lr = lane & 15, lg = lane >> 4;
  const int bm = blockIdx.y * 128, bn = blockIdx.x * 128;

  f32x4 acc[4][4];
#pragma unroll
  for (int m = 0; m < 4; ++m)
#pragma unroll
    for (int n = 0; n < 4; ++n) acc[m][n] = (f32x4){0.f, 0.f, 0.f, 0.f};

  for (int k0 = 0; k0 < K; k0 += 64) {
    __syncthreads();
#pragma unroll
    for (int it = 0; it < 4; ++it) {
      int id = it * 256 + tid;
      int row = id >> 3, c8 = (id & 7) * 8;
      size_t aoff = (size_t)(bm + row) * K + k0 + c8;
      size_t boff = (size_t)(bn + row) * K + k0 + c8;
      *(u16x8v*)&AsH[row][c8] = *(const u16x8v*)(Ah + aoff);
      *(u16x8v*)&AsL[row][c8] = *(const u16x8v*)(Al + aoff);
      *(u16x8v*)&BsH[row][c8] = *(const u16x8v*)(Bth + boff);
      *(u16x8v*)&BsL[row][c8] = *(const u16x8v*)(Btl + boff);
    }
    __syncthreads();
#pragma unroll
    for (int kk = 0; kk < 2; ++kk) {
      bf16x8 afh[4], afl[4], bfh[4], bfl[4];
#pragma unroll
      for (int m = 0; m < 4; ++m) {
        afh[m] = *(const bf16x8*)&AsH[wr * 64 + m * 16 + lr][kk * 32 + lg * 8];
        afl[m] = *(const bf16x8*)&AsL[wr * 64 + m * 16 + lr][kk * 32 + lg * 8];
      }
#pragma unroll
      for (int n = 0; n < 4; ++n) {
        bfh[n] = *(const bf16x8*)&BsH[wc * 64 + n * 16 + lr][kk * 32 + lg * 8];
        bfl[n] = *(const bf16x8*)&BsL[wc * 64 + n * 16 + lr][kk * 32 + lg * 8];
      }
#pragma unroll
      for (int m = 0; m < 4; ++m)
#pragma unroll
        for (int n = 0; n < 4; ++n) {
          acc[m][n] = __builtin_amdgcn_mfma_f32_16x16x32_bf16(afh[m], bfh[n],
                                                              acc[m][n], 0, 0, 0);
          acc[m][n] = __builtin_amdgcn_mfma_f32_16x16x32_bf16(afh[m], bfl[n],
                                                              acc[m][n], 0, 0, 0);
          acc[m][n] = __builtin_amdgcn_mfma_f32_16x16x32_bf16(afl[m], bfh[n],
                                                              acc[m][n], 0, 0, 0);
        }
    }
  }

  // fp32 RoPE on rotary dims (d<32 == fragments n=0,n=1; pair is (n=0,n=1))
  const bool doRope = (MODE == 0) || (MODE == 1 && bn < 1024);
  if (doRope) {
    float inv = __expf(-(float)lr * 0.5756462732485115f);  // ln(10000)/16
#pragma unroll
    for (int m = 0; m < 4; ++m) {
#pragma unroll
      for (int r = 0; r < 4; ++r) {
        int row = bm + wr * 64 + m * 16 + 4 * lg + r;
        int s = row & (SEQ - 1);
        float ang = (float)s * inv;
        float sn, cs;
        __sincosf(ang, &sn, &cs);
        float x1 = acc[m][0][r], x2 = acc[m][1][r];
        acc[m][0][r] = x1 * cs - x2 * sn;
        acc[m][1][r] = x2 * cs + x1 * sn;
      }
    }
  }

#pragma unroll
  for (int m = 0; m < 4; ++m) {
#pragma unroll
    for (int n = 0; n < 4; ++n) {
#pragma unroll
      for (int r = 0; r < 4; ++r) {
        int row = bm + wr * 64 + m * 16 + 4 * lg + r;
        int col = bn + wc * 64 + n * 16 + lr;
        float v = acc[m][n][r];
        if (MODE == 2) {
          CF[(size_t)row * N + col] = v;
        } else if (MODE == 0) {
          int b = row >> 11, s = row & 2047, h = col >> 6, d = col & 63;
          C0[(((size_t)(b * NH + h)) * SEQ + s) * HD + d] = f2bf(v);
        } else {
          int b = row >> 11, s = row & 2047;
          int cc = col;
          u16* dst = C0;
          if (cc >= 1024) { cc -= 1024; dst = C1; }
          int h = cc >> 6, d = cc & 63;
          dst[(((size_t)(b * NH + h)) * SEQ + s) * HD + d] = f2bf(v);
        }
      }
    }
  }
}

// ---------- flash attention (causal), Q/K/V [b,h,s,d] bf16 ----------
__global__ void __launch_bounds__(256, 2)
attn_kernel(const u16* __restrict__ Q, const u16* __restrict__ K,
            const u16* __restrict__ V, u16* __restrict__ Oh,
            u16* __restrict__ Ol) {
  __shared__ u16 Ks[64][72];
  __shared__ u16 Vt[64][72];      // Vt[d][kv]
  __shared__ u16 Ps[4][16][72];   // per-wave P tile
  const int tid = threadIdx.x, lane = tid & 63, wave = tid >> 6;
  const int lr = lane & 15, lg = lane >> 4;
  const int qt = blockIdx.x, bh = blockIdx.y;
  const int b = bh >> 4, h = bh & 15;
  const size_t kvbase = (size_t)bh * SEQ * HD;

  const u16* qrow_p = Q + kvbase + (size_t)(qt * 64 + wave * 16 + lr) * HD;
  bf16x8 qf[2];
  qf[0] = *(const bf16x8*)(qrow_p + lg * 8);
  qf[1] = *(const bf16x8*)(qrow_p + lg * 8 + 32);

  f32x4 oacc[4];
#pragma unroll
  for (int td = 0; td < 4; ++td) oacc[td] = (f32x4){0.f, 0.f, 0.f, 0.f};
  float mreg[4], lreg[4];
#pragma unroll
  for (int r = 0; r < 4; ++r) { mreg[r] = -1e30f; lreg[r] = 0.f; }

  for (int kt = 0; kt <= qt; ++kt) {
    __syncthreads();
#pragma unroll
    for (int it = 0; it < 2; ++it) {
      int id = it * 256 + tid;
      int r = id >> 3, c8 = (id & 7) * 8;
      *(u16x8v*)&Ks[r][c8] =
          *(const u16x8v*)(K + kvbase + (size_t)(kt * 64 + r) * HD + c8);
    }
#pragma unroll
    for (int it = 0; it < 2; ++it) {
      int id = it * 256 + tid;
      int r = id & 63, c8 = (id >> 6) * 8;
      u16x8v v = *(const u16x8v*)(V + kvbase + (size_t)(kt * 64 + r) * HD + c8);
#pragma unroll
      for (int j = 0; j < 8; ++j) Vt[c8 + j][r] = v[j];
    }
    __syncthreads();

    f32x4 sf[4];
#pragma unroll
    for (int tj = 0; tj < 4; ++tj) {
      f32x4 sacc = (f32x4){0.f, 0.f, 0.f, 0.f};
      bf16x8 kf0 = *(const bf16x8*)&Ks[tj * 16 + lr][lg * 8];
      bf16x8 kf1 = *(const bf16x8*)&Ks[tj * 16 + lr][lg * 8 + 32];
      sacc = __builtin_amdgcn_mfma_f32_16x16x32_bf16(qf[0], kf0, sacc, 0, 0, 0);
      sacc = __builtin_amdgcn_mfma_f32_16x16x32_bf16(qf[1], kf1, sacc, 0, 0, 0);
      sf[tj] = sacc * 0.125f;
    }
    if (kt == qt) {
#pragma unroll
      for (int tj = 0; tj < 4; ++tj)
#pragma unroll
        for (int r = 0; r < 4; ++r)
          if (tj * 16 + lr > wave * 16 + 4 * lg + r) sf[tj][r] = -1e30f;
    }
#pragma unroll
    for (int r = 0; r < 4; ++r) {
      float mx = fmaxf(fmaxf(sf[0][r], sf[1][r]), fmaxf(sf[2][r], sf[3][r]));
#pragma unroll
      for (int off = 1; off < 16; off <<= 1) mx = fmaxf(mx, __shfl_xor(mx, off));
      float mn = fmaxf(mreg[r], mx);
      float fac = __expf(mreg[r] - mn);
      mreg[r] = mn;
      float rsum = 0.f;
#pragma unroll
      for (int tj = 0; tj < 4; ++tj) {
        float p = __expf(sf[tj][r] - mn);
        sf[tj][r] = p;
        rsum += p;
      }
#pragma unroll
      for (int off = 1; off < 16; off <<= 1) rsum += __shfl_xor(rsum, off);
      lreg[r] = lreg[r] * fac + rsum;
      // rescale ONLY row r of each output fragment (previous bug: whole f32x4)
#pragma unroll
      for (int td = 0; td < 4; ++td) oacc[td][r] *= fac;
    }
#pragma unroll
    for (int tj = 0; tj < 4; ++tj)
#pragma unroll
      for (int r = 0; r < 4; ++r)
        Ps[wave][4 * lg + r][tj * 16 + lr] = f2bf(sf[tj][r]);
    __syncthreads();
#pragma unroll
    for (int c = 0; c < 2; ++c) {
      bf16x8 pf = *(const bf16x8*)&Ps[wave][lr][c * 32 + lg * 8];
#pragma unroll
      for (int td = 0; td < 4; ++td) {
        bf16x8 vf = *(const bf16x8*)&Vt[td * 16 + lr][c * 32 + lg * 8];
        oacc[td] = __builtin_amdgcn_mfma_f32_16x16x32_bf16(pf, vf, oacc[td], 0, 0, 0);
      }
    }
  }

  // epilogue: O[b, s, h*64+d] as bf16 hi/lo pair (fp32-accurate for final GEMM)
  size_t obase = (size_t)b * SEQ * DIMM + (size_t)h * HD;
#pragma unroll
  for (int r = 0; r < 4; ++r) {
    float inv = 1.0f / lreg[r];
    int s = qt * 64 + wave * 16 + 4 * lg + r;
    size_t rowb = obase + (size_t)s * DIMM;
#pragma unroll
    for (int td = 0; td < 4; ++td) {
      float v = oacc[td][r] * inv;
      u16 hh = f2bf(v);
      Oh[rowb + td * 16 + lr] = hh;
      Ol[rowb + td * 16 + lr] = f2bf(v - bf2f(hh));
    }
  }
}

extern "C" void kernel_launch(void* const* d_in, const int* in_sizes, int n_in,
                              void* d_out, int out_size, void* d_ws, size_t ws_size,
                              hipStream_t stream) {
  const float* x = (const float*)d_in[0];
  const float* wq = (const float*)d_in[1];
  const float* wkv = (const float*)d_in[2];
  const float* wout = (const float*)d_in[3];
  float* out = (float*)d_out;

  u16* ws = (u16*)d_ws;
  const size_t M1 = (size_t)1024 * 1024;
  u16* xh = ws;                    // 4M elems
  u16* xl = xh + 4 * M1;           // 4M
  u16* wqTh = xl + 4 * M1;         // 1M
  u16* wqTl = wqTh + M1;           // 1M
  u16* wkvTh = wqTl + M1;          // 2M
  u16* wkvTl = wkvTh + 2 * M1;     // 2M
  u16* Qb = wkvTl + 2 * M1;        // 4M
  u16* Kb = Qb + 4 * M1;           // 4M
  u16* Vb = Kb + 4 * M1;           // 4M
  // overlays (dead regions reused):
  u16* woutTh = wqTh;              // after QKV gemms, wqT region is dead
  u16* woutTl = wqTl;
  u16* Ohh = xh;                   // after QKV gemms, x region is dead
  u16* Oll = xl;

  conv_x_split<<<4096, 256, 0, stream>>>(x, xh, xl);
  conv_wT_split<<<dim3(32, 32), 256, 0, stream>>>(wq, wqTh, wqTl, 1024, 1024);
  conv_wT_split<<<dim3(64, 32), 256, 0, stream>>>(wkv, wkvTh, wkvTl, 1024, 2048);

  gemm3<0><<<dim3(8, 32), 256, 0, stream>>>(xh, xl, wqTh, wqTl, Qb, nullptr,
                                            nullptr, 4096, 1024, 1024);
  gemm3<1><<<dim3(16, 32), 256, 0, stream>>>(xh, xl, wkvTh, wkvTl, Kb, Vb,
                                             nullptr, 4096, 2048, 1024);

  conv_wT_split<<<dim3(32, 32), 256, 0, stream>>>(wout, woutTh, woutTl, 1024, 1024);

  attn_kernel<<<dim3(32, 32), 256, 0, stream>>>(Qb, Kb, Vb, Ohh, Oll);

  gemm3<2><<<dim3(8, 32), 256, 0, stream>>>(Ohh, Oll, woutTh, woutTl, nullptr,
                                            nullptr, out, 4096, 1024, 1024);
}

// Round 7
// 261.483 us; speedup vs baseline: 1.1100x; 1.1100x over previous
//
#include <hip/hip_runtime.h>

typedef unsigned short u16;
typedef __bf16 bf16x8 __attribute__((ext_vector_type(8)));
typedef unsigned short u16x8v __attribute__((ext_vector_type(8)));
typedef unsigned short u16x4v __attribute__((ext_vector_type(4)));
typedef float f32x4 __attribute__((ext_vector_type(4)));

#define SEQ 2048
#define NH 16
#define HD 64
#define DIMM 1024

__device__ __forceinline__ u16 f2bf(float f) {
  unsigned u = __builtin_bit_cast(unsigned, f);
  u += 0x7fffu + ((u >> 16) & 1u);
  return (u16)(u >> 16);
}
__device__ __forceinline__ float bf2f(u16 b) {
  return __builtin_bit_cast(float, ((unsigned)b) << 16);
}

// ---------- split-convert x (f32 -> bf16 hi + bf16 lo) ----------
__global__ void conv_x_split(const float* __restrict__ x, u16* __restrict__ oh,
                             u16* __restrict__ ol) {
  size_t i = (size_t)blockIdx.x * 256 + threadIdx.x;
  f32x4 v = *(const f32x4*)(x + i * 4);
  u16x4v h, l;
#pragma unroll
  for (int j = 0; j < 4; ++j) {
    h[j] = f2bf(v[j]);
    l[j] = f2bf(v[j] - bf2f(h[j]));
  }
  *(u16x4v*)(oh + i * 4) = h;
  *(u16x4v*)(ol + i * 4) = l;
}

// ---------- transpose + split: W[K][N] f32 -> Wt{h,l}[N][K] bf16 ----------
__global__ void conv_wT_split(const float* __restrict__ W, u16* __restrict__ Wth,
                              u16* __restrict__ Wtl, int Kd, int Nd) {
  __shared__ float t[32][33];
  int n0 = blockIdx.x * 32, k0 = blockIdx.y * 32;
  int c = threadIdx.x & 31, r8 = threadIdx.x >> 5;
#pragma unroll
  for (int rr = 0; rr < 32; rr += 8)
    t[r8 + rr][c] = W[(size_t)(k0 + r8 + rr) * Nd + n0 + c];
  __syncthreads();
#pragma unroll
  for (int rr = 0; rr < 32; rr += 8) {
    float v = t[c][r8 + rr];
    u16 h = f2bf(v);
    Wth[(size_t)(n0 + r8 + rr) * Kd + k0 + c] = h;
    Wtl[(size_t)(n0 + r8 + rr) * Kd + k0 + c] = f2bf(v - bf2f(h));
  }
}

// ---------- 3-term split GEMM: C = Ah@Bh + Ah@Bl + Al@Bh (fp32-accurate) ----
// A{h,l}[M][K] bf16 row-major, Bt{h,l}[N][K] bf16 row-major (B transposed).
// MODE 0: Q  -> rope in fp32, write bf16 C0 [b,h,s,d]
// MODE 1: KV -> cols<1024: rope, write K to C0; cols>=1024: write V to C1
// MODE 2: write f32 to CF[M][N]
template <int MODE>
__global__ void __launch_bounds__(256, 2)
gemm3(const u16* __restrict__ Ah, const u16* __restrict__ Al,
      const u16* __restrict__ Bth, const u16* __restrict__ Btl,
      u16* __restrict__ C0, u16* __restrict__ C1, float* __restrict__ CF,
      int M, int N, int K) {
  __shared__ u16 AsH[128][72];
  __shared__ u16 AsL[128][72];
  __shared__ u16 BsH[128][72];
  __shared__ u16 BsL[128][72];
  const int tid = threadIdx.x;
  const int lane = tid & 63, wave = tid >> 6;
  const int wr = wave >> 1, wc = wave & 1;
  const int lr = lane & 15, lg = lane >> 4;
  const int bm = blockIdx.y * 128, bn = blockIdx.x * 128;

  f32x4 acc[4][4];
#pragma unroll
  for (int m = 0; m < 4; ++m)
#pragma unroll
    for (int n = 0; n < 4; ++n) acc[m][n] = (f32x4){0.f, 0.f, 0.f, 0.f};

  for (int k0 = 0; k0 < K; k0 += 64) {
    __syncthreads();
#pragma unroll
    for (int it = 0; it < 4; ++it) {
      int id = it * 256 + tid;
      int row = id >> 3, c8 = (id & 7) * 8;
      size_t aoff = (size_t)(bm + row) * K + k0 + c8;
      size_t boff = (size_t)(bn + row) * K + k0 + c8;
      *(u16x8v*)&AsH[row][c8] = *(const u16x8v*)(Ah + aoff);
      *(u16x8v*)&AsL[row][c8] = *(const u16x8v*)(Al + aoff);
      *(u16x8v*)&BsH[row][c8] = *(const u16x8v*)(Bth + boff);
      *(u16x8v*)&BsL[row][c8] = *(const u16x8v*)(Btl + boff);
    }
    __syncthreads();
#pragma unroll
    for (int kk = 0; kk < 2; ++kk) {
      bf16x8 afh[4], afl[4], bfh[4], bfl[4];
#pragma unroll
      for (int m = 0; m < 4; ++m) {
        afh[m] = *(const bf16x8*)&AsH[wr * 64 + m * 16 + lr][kk * 32 + lg * 8];
        afl[m] = *(const bf16x8*)&AsL[wr * 64 + m * 16 + lr][kk * 32 + lg * 8];
      }
#pragma unroll
      for (int n = 0; n < 4; ++n) {
        bfh[n] = *(const bf16x8*)&BsH[wc * 64 + n * 16 + lr][kk * 32 + lg * 8];
        bfl[n] = *(const bf16x8*)&BsL[wc * 64 + n * 16 + lr][kk * 32 + lg * 8];
      }
#pragma unroll
      for (int m = 0; m < 4; ++m)
#pragma unroll
        for (int n = 0; n < 4; ++n) {
          acc[m][n] = __builtin_amdgcn_mfma_f32_16x16x32_bf16(afh[m], bfh[n],
                                                              acc[m][n], 0, 0, 0);
          acc[m][n] = __builtin_amdgcn_mfma_f32_16x16x32_bf16(afh[m], bfl[n],
                                                              acc[m][n], 0, 0, 0);
          acc[m][n] = __builtin_amdgcn_mfma_f32_16x16x32_bf16(afl[m], bfh[n],
                                                              acc[m][n], 0, 0, 0);
        }
    }
  }

  // fp32 RoPE on rotary dims (d<32 == fragments n=0,n=1; pair is (n=0,n=1))
  const bool doRope = (MODE == 0) || (MODE == 1 && bn < 1024);
  if (doRope) {
    float inv = __expf(-(float)lr * 0.5756462732485115f);  // ln(10000)/16
#pragma unroll
    for (int m = 0; m < 4; ++m) {
#pragma unroll
      for (int r = 0; r < 4; ++r) {
        int row = bm + wr * 64 + m * 16 + 4 * lg + r;
        int s = row & (SEQ - 1);
        float ang = (float)s * inv;
        float sn, cs;
        __sincosf(ang, &sn, &cs);
        float x1 = acc[m][0][r], x2 = acc[m][1][r];
        acc[m][0][r] = x1 * cs - x2 * sn;
        acc[m][1][r] = x2 * cs + x1 * sn;
      }
    }
  }

#pragma unroll
  for (int m = 0; m < 4; ++m) {
#pragma unroll
    for (int n = 0; n < 4; ++n) {
#pragma unroll
      for (int r = 0; r < 4; ++r) {
        int row = bm + wr * 64 + m * 16 + 4 * lg + r;
        int col = bn + wc * 64 + n * 16 + lr;
        float v = acc[m][n][r];
        if (MODE == 2) {
          CF[(size_t)row * N + col] = v;
        } else if (MODE == 0) {
          int b = row >> 11, s = row & 2047, h = col >> 6, d = col & 63;
          C0[(((size_t)(b * NH + h)) * SEQ + s) * HD + d] = f2bf(v);
        } else {
          int b = row >> 11, s = row & 2047;
          int cc = col;
          u16* dst = C0;
          if (cc >= 1024) { cc -= 1024; dst = C1; }
          int h = cc >> 6, d = cc & 63;
          dst[(((size_t)(b * NH + h)) * SEQ + s) * HD + d] = f2bf(v);
        }
      }
    }
  }
}

// ---------- flash attention (causal), Q/K/V [b,h,s,d] bf16 ----------
// Pair-balanced: block handles qtA = blockIdx.x (0..15) and qtB = 31-blockIdx.x
// sequentially -> uniform 33 kv-tile iterations per block, no causal tail.
__global__ void __launch_bounds__(256, 2)
attn_kernel(const u16* __restrict__ Q, const u16* __restrict__ K,
            const u16* __restrict__ V, u16* __restrict__ Oh,
            u16* __restrict__ Ol) {
  __shared__ u16 Ks[64][72];
  __shared__ u16 Vt[64][72];      // Vt[d][kv]
  __shared__ u16 Ps[4][16][72];   // per-wave P tile
  const int tid = threadIdx.x, lane = tid & 63, wave = tid >> 6;
  const int lr = lane & 15, lg = lane >> 4;
  const int bh = blockIdx.y;
  const int b = bh >> 4, h = bh & 15;
  const size_t kvbase = (size_t)bh * SEQ * HD;
  const size_t obase = (size_t)b * SEQ * DIMM + (size_t)h * HD;

#pragma unroll 1
  for (int phase = 0; phase < 2; ++phase) {
    const int qt = phase == 0 ? blockIdx.x : 31 - blockIdx.x;

    const u16* qrow_p = Q + kvbase + (size_t)(qt * 64 + wave * 16 + lr) * HD;
    bf16x8 qf[2];
    qf[0] = *(const bf16x8*)(qrow_p + lg * 8);
    qf[1] = *(const bf16x8*)(qrow_p + lg * 8 + 32);

    f32x4 oacc[4];
#pragma unroll
    for (int td = 0; td < 4; ++td) oacc[td] = (f32x4){0.f, 0.f, 0.f, 0.f};
    float mreg[4], lreg[4];
#pragma unroll
    for (int r = 0; r < 4; ++r) { mreg[r] = -1e30f; lreg[r] = 0.f; }

    for (int kt = 0; kt <= qt; ++kt) {
      __syncthreads();
#pragma unroll
      for (int it = 0; it < 2; ++it) {
        int id = it * 256 + tid;
        int r = id >> 3, c8 = (id & 7) * 8;
        *(u16x8v*)&Ks[r][c8] =
            *(const u16x8v*)(K + kvbase + (size_t)(kt * 64 + r) * HD + c8);
      }
#pragma unroll
      for (int it = 0; it < 2; ++it) {
        int id = it * 256 + tid;
        int r = id & 63, c8 = (id >> 6) * 8;
        u16x8v v = *(const u16x8v*)(V + kvbase + (size_t)(kt * 64 + r) * HD + c8);
#pragma unroll
        for (int j = 0; j < 8; ++j) Vt[c8 + j][r] = v[j];
      }
      __syncthreads();

      f32x4 sf[4];
#pragma unroll
      for (int tj = 0; tj < 4; ++tj) {
        f32x4 sacc = (f32x4){0.f, 0.f, 0.f, 0.f};
        bf16x8 kf0 = *(const bf16x8*)&Ks[tj * 16 + lr][lg * 8];
        bf16x8 kf1 = *(const bf16x8*)&Ks[tj * 16 + lr][lg * 8 + 32];
        sacc = __builtin_amdgcn_mfma_f32_16x16x32_bf16(qf[0], kf0, sacc, 0, 0, 0);
        sacc = __builtin_amdgcn_mfma_f32_16x16x32_bf16(qf[1], kf1, sacc, 0, 0, 0);
        sf[tj] = sacc * 0.125f;
      }
      if (kt == qt) {
#pragma unroll
        for (int tj = 0; tj < 4; ++tj)
#pragma unroll
          for (int r = 0; r < 4; ++r)
            if (tj * 16 + lr > wave * 16 + 4 * lg + r) sf[tj][r] = -1e30f;
      }
#pragma unroll
      for (int r = 0; r < 4; ++r) {
        float mx = fmaxf(fmaxf(sf[0][r], sf[1][r]), fmaxf(sf[2][r], sf[3][r]));
#pragma unroll
        for (int off = 1; off < 16; off <<= 1) mx = fmaxf(mx, __shfl_xor(mx, off));
        float mn = fmaxf(mreg[r], mx);
        float fac = __expf(mreg[r] - mn);
        mreg[r] = mn;
        float rsum = 0.f;
#pragma unroll
        for (int tj = 0; tj < 4; ++tj) {
          float p = __expf(sf[tj][r] - mn);
          sf[tj][r] = p;
          rsum += p;
        }
#pragma unroll
        for (int off = 1; off < 16; off <<= 1) rsum += __shfl_xor(rsum, off);
        lreg[r] = lreg[r] * fac + rsum;
#pragma unroll
        for (int td = 0; td < 4; ++td) oacc[td][r] *= fac;
      }
#pragma unroll
      for (int tj = 0; tj < 4; ++tj)
#pragma unroll
        for (int r = 0; r < 4; ++r)
          Ps[wave][4 * lg + r][tj * 16 + lr] = f2bf(sf[tj][r]);
      __syncthreads();
#pragma unroll
      for (int c = 0; c < 2; ++c) {
        bf16x8 pf = *(const bf16x8*)&Ps[wave][lr][c * 32 + lg * 8];
#pragma unroll
        for (int td = 0; td < 4; ++td) {
          bf16x8 vf = *(const bf16x8*)&Vt[td * 16 + lr][c * 32 + lg * 8];
          oacc[td] = __builtin_amdgcn_mfma_f32_16x16x32_bf16(pf, vf, oacc[td], 0, 0, 0);
        }
      }
    }

    // epilogue: O[b, s, h*64+d] as bf16 hi/lo pair (fp32-accurate final GEMM)
#pragma unroll
    for (int r = 0; r < 4; ++r) {
      float inv = 1.0f / lreg[r];
      int s = qt * 64 + wave * 16 + 4 * lg + r;
      size_t rowb = obase + (size_t)s * DIMM;
#pragma unroll
      for (int td = 0; td < 4; ++td) {
        float v = oacc[td][r] * inv;
        u16 hh = f2bf(v);
        Oh[rowb + td * 16 + lr] = hh;
        Ol[rowb + td * 16 + lr] = f2bf(v - bf2f(hh));
      }
    }
  }
}

extern "C" void kernel_launch(void* const* d_in, const int* in_sizes, int n_in,
                              void* d_out, int out_size, void* d_ws, size_t ws_size,
                              hipStream_t stream) {
  const float* x = (const float*)d_in[0];
  const float* wq = (const float*)d_in[1];
  const float* wkv = (const float*)d_in[2];
  const float* wout = (const float*)d_in[3];
  float* out = (float*)d_out;

  u16* ws = (u16*)d_ws;
  const size_t M1 = (size_t)1024 * 1024;
  u16* xh = ws;                    // 4M elems
  u16* xl = xh + 4 * M1;           // 4M
  u16* wqTh = xl + 4 * M1;         // 1M
  u16* wqTl = wqTh + M1;           // 1M
  u16* wkvTh = wqTl + M1;          // 2M
  u16* wkvTl = wkvTh + 2 * M1;     // 2M
  u16* Qb = wkvTl + 2 * M1;        // 4M
  u16* Kb = Qb + 4 * M1;           // 4M
  u16* Vb = Kb + 4 * M1;           // 4M
  // overlays (dead regions reused):
  u16* woutTh = wqTh;              // after QKV gemms, wqT region is dead
  u16* woutTl = wqTl;
  u16* Ohh = xh;                   // after QKV gemms, x region is dead
  u16* Oll = xl;

  conv_x_split<<<4096, 256, 0, stream>>>(x, xh, xl);
  conv_wT_split<<<dim3(32, 32), 256, 0, stream>>>(wq, wqTh, wqTl, 1024, 1024);
  conv_wT_split<<<dim3(64, 32), 256, 0, stream>>>(wkv, wkvTh, wkvTl, 1024, 2048);

  gemm3<0><<<dim3(8, 32), 256, 0, stream>>>(xh, xl, wqTh, wqTl, Qb, nullptr,
                                            nullptr, 4096, 1024, 1024);
  gemm3<1><<<dim3(16, 32), 256, 0, stream>>>(xh, xl, wkvTh, wkvTl, Kb, Vb,
                                             nullptr, 4096, 2048, 1024);

  conv_wT_split<<<dim3(32, 32), 256, 0, stream>>>(wout, woutTh, woutTl, 1024, 1024);

  attn_kernel<<<dim3(16, 32), 256, 0, stream>>>(Qb, Kb, Vb, Ohh, Oll);

  gemm3<2><<<dim3(8, 32), 256, 0, stream>>>(Ohh, Oll, woutTh, woutTl, nullptr,
                                            nullptr, out, 4096, 1024, 1024);
}

// Round 8
// 240.236 us; speedup vs baseline: 1.2081x; 1.0884x over previous
//
#include <hip/hip_runtime.h>

typedef unsigned short u16;
typedef __bf16 bf16x8 __attribute__((ext_vector_type(8)));
typedef unsigned short u16x8v __attribute__((ext_vector_type(8)));
typedef unsigned short u16x4v __attribute__((ext_vector_type(4)));
typedef float f32x4 __attribute__((ext_vector_type(4)));

#define SEQ 2048
#define NH 16
#define HD 64
#define DIMM 1024

__device__ __forceinline__ u16 f2bf(float f) {
  unsigned u = __builtin_bit_cast(unsigned, f);
  u += 0x7fffu + ((u >> 16) & 1u);
  return (u16)(u >> 16);
}
__device__ __forceinline__ float bf2f(u16 b) {
  return __builtin_bit_cast(float, ((unsigned)b) << 16);
}

// ---------- split-convert x (f32 -> bf16 hi + bf16 lo) ----------
__global__ void conv_x_split(const float* __restrict__ x, u16* __restrict__ oh,
                             u16* __restrict__ ol) {
  size_t i = (size_t)blockIdx.x * 256 + threadIdx.x;
  f32x4 v = *(const f32x4*)(x + i * 4);
  u16x4v h, l;
#pragma unroll
  for (int j = 0; j < 4; ++j) {
    h[j] = f2bf(v[j]);
    l[j] = f2bf(v[j] - bf2f(h[j]));
  }
  *(u16x4v*)(oh + i * 4) = h;
  *(u16x4v*)(ol + i * 4) = l;
}

// ---------- transpose + split: W[K][N] f32 -> Wt{h,l}[N][K] bf16 ----------
__global__ void conv_wT_split(const float* __restrict__ W, u16* __restrict__ Wth,
                              u16* __restrict__ Wtl, int Kd, int Nd) {
  __shared__ float t[32][33];
  int n0 = blockIdx.x * 32, k0 = blockIdx.y * 32;
  int c = threadIdx.x & 31, r8 = threadIdx.x >> 5;
#pragma unroll
  for (int rr = 0; rr < 32; rr += 8)
    t[r8 + rr][c] = W[(size_t)(k0 + r8 + rr) * Nd + n0 + c];
  __syncthreads();
#pragma unroll
  for (int rr = 0; rr < 32; rr += 8) {
    float v = t[c][r8 + rr];
    u16 h = f2bf(v);
    Wth[(size_t)(n0 + r8 + rr) * Kd + k0 + c] = h;
    Wtl[(size_t)(n0 + r8 + rr) * Kd + k0 + c] = f2bf(v - bf2f(h));
  }
}

// ---------- transpose (no split): W[K][N] f32 -> Wt[N][K] bf16 ----------
__global__ void conv_wT(const float* __restrict__ W, u16* __restrict__ Wt,
                        int Kd, int Nd) {
  __shared__ float t[32][33];
  int n0 = blockIdx.x * 32, k0 = blockIdx.y * 32;
  int c = threadIdx.x & 31, r8 = threadIdx.x >> 5;
#pragma unroll
  for (int rr = 0; rr < 32; rr += 8)
    t[r8 + rr][c] = W[(size_t)(k0 + r8 + rr) * Nd + n0 + c];
  __syncthreads();
#pragma unroll
  for (int rr = 0; rr < 32; rr += 8)
    Wt[(size_t)(n0 + r8 + rr) * Kd + k0 + c] = f2bf(t[c][r8 + rr]);
}

// ---------- 3-term split GEMM (fp32-accurate), QKV projections ----------
// MODE 0: Q  -> rope in fp32, write bf16 C0 [b,h,s,d]
// MODE 1: KV -> cols<1024: rope, write K to C0; cols>=1024: write V to C1
template <int MODE>
__global__ void __launch_bounds__(256, 2)
gemm3(const u16* __restrict__ Ah, const u16* __restrict__ Al,
      const u16* __restrict__ Bth, const u16* __restrict__ Btl,
      u16* __restrict__ C0, u16* __restrict__ C1, int M, int N, int K) {
  __shared__ u16 AsH[128][72];
  __shared__ u16 AsL[128][72];
  __shared__ u16 BsH[128][72];
  __shared__ u16 BsL[128][72];
  const int tid = threadIdx.x;
  const int lane = tid & 63, wave = tid >> 6;
  const int wr = wave >> 1, wc = wave & 1;
  const int lr = lane & 15, lg = lane >> 4;
  const int bm = blockIdx.y * 128, bn = blockIdx.x * 128;

  f32x4 acc[4][4];
#pragma unroll
  for (int m = 0; m < 4; ++m)
#pragma unroll
    for (int n = 0; n < 4; ++n) acc[m][n] = (f32x4){0.f, 0.f, 0.f, 0.f};

  for (int k0 = 0; k0 < K; k0 += 64) {
    __syncthreads();
#pragma unroll
    for (int it = 0; it < 4; ++it) {
      int id = it * 256 + tid;
      int row = id >> 3, c8 = (id & 7) * 8;
      size_t aoff = (size_t)(bm + row) * K + k0 + c8;
      size_t boff = (size_t)(bn + row) * K + k0 + c8;
      *(u16x8v*)&AsH[row][c8] = *(const u16x8v*)(Ah + aoff);
      *(u16x8v*)&AsL[row][c8] = *(const u16x8v*)(Al + aoff);
      *(u16x8v*)&BsH[row][c8] = *(const u16x8v*)(Bth + boff);
      *(u16x8v*)&BsL[row][c8] = *(const u16x8v*)(Btl + boff);
    }
    __syncthreads();
#pragma unroll
    for (int kk = 0; kk < 2; ++kk) {
      bf16x8 afh[4], afl[4], bfh[4], bfl[4];
#pragma unroll
      for (int m = 0; m < 4; ++m) {
        afh[m] = *(const bf16x8*)&AsH[wr * 64 + m * 16 + lr][kk * 32 + lg * 8];
        afl[m] = *(const bf16x8*)&AsL[wr * 64 + m * 16 + lr][kk * 32 + lg * 8];
      }
#pragma unroll
      for (int n = 0; n < 4; ++n) {
        bfh[n] = *(const bf16x8*)&BsH[wc * 64 + n * 16 + lr][kk * 32 + lg * 8];
        bfl[n] = *(const bf16x8*)&BsL[wc * 64 + n * 16 + lr][kk * 32 + lg * 8];
      }
#pragma unroll
      for (int m = 0; m < 4; ++m)
#pragma unroll
        for (int n = 0; n < 4; ++n) {
          acc[m][n] = __builtin_amdgcn_mfma_f32_16x16x32_bf16(afh[m], bfh[n],
                                                              acc[m][n], 0, 0, 0);
          acc[m][n] = __builtin_amdgcn_mfma_f32_16x16x32_bf16(afh[m], bfl[n],
                                                              acc[m][n], 0, 0, 0);
          acc[m][n] = __builtin_amdgcn_mfma_f32_16x16x32_bf16(afl[m], bfh[n],
                                                              acc[m][n], 0, 0, 0);
        }
    }
  }

  // fp32 RoPE on rotary dims (d<32 == fragments n=0,n=1)
  const bool doRope = (MODE == 0) || (MODE == 1 && bn < 1024);
  if (doRope) {
    float inv = __expf(-(float)lr * 0.5756462732485115f);  // ln(10000)/16
#pragma unroll
    for (int m = 0; m < 4; ++m) {
#pragma unroll
      for (int r = 0; r < 4; ++r) {
        int row = bm + wr * 64 + m * 16 + 4 * lg + r;
        int s = row & (SEQ - 1);
        float ang = (float)s * inv;
        float sn, cs;
        __sincosf(ang, &sn, &cs);
        float x1 = acc[m][0][r], x2 = acc[m][1][r];
        acc[m][0][r] = x1 * cs - x2 * sn;
        acc[m][1][r] = x2 * cs + x1 * sn;
      }
    }
  }

#pragma unroll
  for (int m = 0; m < 4; ++m) {
#pragma unroll
    for (int n = 0; n < 4; ++n) {
#pragma unroll
      for (int r = 0; r < 4; ++r) {
        int row = bm + wr * 64 + m * 16 + 4 * lg + r;
        int col = bn + wc * 64 + n * 16 + lr;
        float v = acc[m][n][r];
        if (MODE == 0) {
          int b = row >> 11, s = row & 2047, h = col >> 6, d = col & 63;
          C0[(((size_t)(b * NH + h)) * SEQ + s) * HD + d] = f2bf(v);
        } else {
          int b = row >> 11, s = row & 2047;
          int cc = col;
          u16* dst = C0;
          if (cc >= 1024) { cc -= 1024; dst = C1; }
          int h = cc >> 6, d = cc & 63;
          dst[(((size_t)(b * NH + h)) * SEQ + s) * HD + d] = f2bf(v);
        }
      }
    }
  }
}

// ---------- single-term GEMM for output projection ----------
__global__ void __launch_bounds__(256, 2)
gemm1(const u16* __restrict__ A, const u16* __restrict__ Bt,
      float* __restrict__ CF, int M, int N, int K) {
  __shared__ u16 As[128][72];
  __shared__ u16 Bs[128][72];
  const int tid = threadIdx.x;
  const int lane = tid & 63, wave = tid >> 6;
  const int wr = wave >> 1, wc = wave & 1;
  const int lr = lane & 15, lg = lane >> 4;
  const int bm = blockIdx.y * 128, bn = blockIdx.x * 128;

  f32x4 acc[4][4];
#pragma unroll
  for (int m = 0; m < 4; ++m)
#pragma unroll
    for (int n = 0; n < 4; ++n) acc[m][n] = (f32x4){0.f, 0.f, 0.f, 0.f};

  for (int k0 = 0; k0 < K; k0 += 64) {
    __syncthreads();
#pragma unroll
    for (int it = 0; it < 2; ++it) {
      int id = it * 512 + tid * 2;
      int row = id >> 3, c8 = (id & 6) * 8;  // 2 vec8 per thread, adjacent
      size_t aoff = (size_t)(bm + row) * K + k0 + c8;
      size_t boff = (size_t)(bn + row) * K + k0 + c8;
      *(u16x8v*)&As[row][c8] = *(const u16x8v*)(A + aoff);
      *(u16x8v*)&As[row][c8 + 8] = *(const u16x8v*)(A + aoff + 8);
      *(u16x8v*)&Bs[row][c8] = *(const u16x8v*)(Bt + boff);
      *(u16x8v*)&Bs[row][c8 + 8] = *(const u16x8v*)(Bt + boff + 8);
    }
    __syncthreads();
#pragma unroll
    for (int kk = 0; kk < 2; ++kk) {
      bf16x8 af[4], bfr[4];
#pragma unroll
      for (int m = 0; m < 4; ++m)
        af[m] = *(const bf16x8*)&As[wr * 64 + m * 16 + lr][kk * 32 + lg * 8];
#pragma unroll
      for (int n = 0; n < 4; ++n)
        bfr[n] = *(const bf16x8*)&Bs[wc * 64 + n * 16 + lr][kk * 32 + lg * 8];
#pragma unroll
      for (int m = 0; m < 4; ++m)
#pragma unroll
        for (int n = 0; n < 4; ++n)
          acc[m][n] = __builtin_amdgcn_mfma_f32_16x16x32_bf16(af[m], bfr[n],
                                                              acc[m][n], 0, 0, 0);
    }
  }

#pragma unroll
  for (int m = 0; m < 4; ++m)
#pragma unroll
    for (int n = 0; n < 4; ++n)
#pragma unroll
      for (int r = 0; r < 4; ++r) {
        int row = bm + wr * 64 + m * 16 + 4 * lg + r;
        int col = bn + wc * 64 + n * 16 + lr;
        CF[(size_t)row * N + col] = acc[m][n][r];
      }
}

// ---------- flash attention, KV-split x2 + causal pairing ----------
// Block bx in [0,32): phase0 = (qt=bx, kv tiles [0, ceil((qt+1)/2)) ),
// phase1 = (qt=31-bx, kv tiles [ceil((qt+1)/2), qt+1) ). 16/17 iters uniform.
// Writes premultiplied partials: Opart[half][bh][s][64] f32, m/l in ml[4][32][SEQ].
__global__ void __launch_bounds__(256, 2)
attn_kernel(const u16* __restrict__ Q, const u16* __restrict__ K,
            const u16* __restrict__ V, float* __restrict__ Op0,
            float* __restrict__ Op1, float* __restrict__ ml) {
  __shared__ u16 Ks[64][72];
  __shared__ u16 Vt[64][72];      // Vt[d][kv]
  __shared__ u16 Ps[4][16][72];   // per-wave P tile
  const int tid = threadIdx.x, lane = tid & 63, wave = tid >> 6;
  const int lr = lane & 15, lg = lane >> 4;
  const int bh = blockIdx.y;
  const size_t kvbase = (size_t)bh * SEQ * HD;

#pragma unroll 1
  for (int phase = 0; phase < 2; ++phase) {
    const int qt = phase == 0 ? (int)blockIdx.x : 31 - (int)blockIdx.x;
    const int ktmid = (qt + 2) >> 1;  // ceil((qt+1)/2)
    const int ktbegin = phase == 0 ? 0 : ktmid;
    const int ktend = phase == 0 ? ktmid : qt + 1;
    float* __restrict__ Opart = phase == 0 ? Op0 : Op1;
    float* __restrict__ mdst = ml + phase * (32 * SEQ);
    float* __restrict__ ldst = ml + 2 * 32 * SEQ + phase * (32 * SEQ);

    const u16* qrow_p = Q + kvbase + (size_t)(qt * 64 + wave * 16 + lr) * HD;
    bf16x8 qf[2];
    qf[0] = *(const bf16x8*)(qrow_p + lg * 8);
    qf[1] = *(const bf16x8*)(qrow_p + lg * 8 + 32);

    f32x4 oacc[4];
#pragma unroll
    for (int td = 0; td < 4; ++td) oacc[td] = (f32x4){0.f, 0.f, 0.f, 0.f};
    float mreg[4], lreg[4];
#pragma unroll
    for (int r = 0; r < 4; ++r) { mreg[r] = -1e30f; lreg[r] = 0.f; }

#pragma unroll 1
    for (int kt = ktbegin; kt < ktend; ++kt) {
      __syncthreads();
#pragma unroll
      for (int it = 0; it < 2; ++it) {
        int id = it * 256 + tid;
        int r = id >> 3, c8 = (id & 7) * 8;
        *(u16x8v*)&Ks[r][c8] =
            *(const u16x8v*)(K + kvbase + (size_t)(kt * 64 + r) * HD + c8);
      }
#pragma unroll
      for (int it = 0; it < 2; ++it) {
        int id = it * 256 + tid;
        int r = id & 63, c8 = (id >> 6) * 8;
        u16x8v v = *(const u16x8v*)(V + kvbase + (size_t)(kt * 64 + r) * HD + c8);
#pragma unroll
        for (int j = 0; j < 8; ++j) Vt[c8 + j][r] = v[j];
      }
      __syncthreads();

      f32x4 sf[4];
#pragma unroll
      for (int tj = 0; tj < 4; ++tj) {
        f32x4 sacc = (f32x4){0.f, 0.f, 0.f, 0.f};
        bf16x8 kf0 = *(const bf16x8*)&Ks[tj * 16 + lr][lg * 8];
        bf16x8 kf1 = *(const bf16x8*)&Ks[tj * 16 + lr][lg * 8 + 32];
        sacc = __builtin_amdgcn_mfma_f32_16x16x32_bf16(qf[0], kf0, sacc, 0, 0, 0);
        sacc = __builtin_amdgcn_mfma_f32_16x16x32_bf16(qf[1], kf1, sacc, 0, 0, 0);
        sf[tj] = sacc * 0.125f;
      }
      if (kt == qt) {  // diagonal tile (tile origins equal -> within-tile compare)
#pragma unroll
        for (int tj = 0; tj < 4; ++tj)
#pragma unroll
          for (int r = 0; r < 4; ++r)
            if (tj * 16 + lr > wave * 16 + 4 * lg + r) sf[tj][r] = -1e30f;
      }
#pragma unroll
      for (int r = 0; r < 4; ++r) {
        float mx = fmaxf(fmaxf(sf[0][r], sf[1][r]), fmaxf(sf[2][r], sf[3][r]));
#pragma unroll
        for (int off = 1; off < 16; off <<= 1) mx = fmaxf(mx, __shfl_xor(mx, off));
        float mn = fmaxf(mreg[r], mx);
        float fac = __expf(mreg[r] - mn);
        mreg[r] = mn;
        float rsum = 0.f;
#pragma unroll
        for (int tj = 0; tj < 4; ++tj) {
          float p = __expf(sf[tj][r] - mn);
          sf[tj][r] = p;
          rsum += p;
        }
#pragma unroll
        for (int off = 1; off < 16; off <<= 1) rsum += __shfl_xor(rsum, off);
        lreg[r] = lreg[r] * fac + rsum;
#pragma unroll
        for (int td = 0; td < 4; ++td) oacc[td][r] *= fac;
      }
#pragma unroll
      for (int tj = 0; tj < 4; ++tj)
#pragma unroll
        for (int r = 0; r < 4; ++r)
          Ps[wave][4 * lg + r][tj * 16 + lr] = f2bf(sf[tj][r]);
      // no barrier: Ps is wave-private (same-wave ds write->read order), Vt synced
#pragma unroll
      for (int c = 0; c < 2; ++c) {
        bf16x8 pf = *(const bf16x8*)&Ps[wave][lr][c * 32 + lg * 8];
#pragma unroll
        for (int td = 0; td < 4; ++td) {
          bf16x8 vf = *(const bf16x8*)&Vt[td * 16 + lr][c * 32 + lg * 8];
          oacc[td] = __builtin_amdgcn_mfma_f32_16x16x32_bf16(pf, vf, oacc[td], 0, 0, 0);
        }
      }
    }

    // partial epilogue: premultiplied O (f32) + m/l sentinels
#pragma unroll
    for (int r = 0; r < 4; ++r) {
      int s = qt * 64 + wave * 16 + 4 * lg + r;
      size_t rowb = kvbase + (size_t)s * HD;  // Opart is [32][SEQ][64]
#pragma unroll
      for (int td = 0; td < 4; ++td) Opart[rowb + td * 16 + lr] = oacc[td][r];
      if (lr == 0) {
        mdst[bh * SEQ + s] = mreg[r];
        ldst[bh * SEQ + s] = lreg[r];
      }
    }
  }
}

// ---------- merge the two KV-half partials, write bf16 O [b,s,h*64+d] ----------
__global__ void merge_kernel(const float* __restrict__ Op0,
                             const float* __restrict__ Op1,
                             const float* __restrict__ ml,
                             u16* __restrict__ O) {
  int i = blockIdx.x * 256 + threadIdx.x;  // 1M threads, 4 f32 each
  int row = i >> 4;                        // bh*SEQ + s
  int d0 = (i & 15) * 4;
  size_t base = (size_t)row * 64 + d0;
  f32x4 o1 = *(const f32x4*)(Op0 + base);
  f32x4 o2 = *(const f32x4*)(Op1 + base);
  const int HS = 32 * SEQ;
  float m1 = ml[row], m2 = ml[HS + row];
  float l1 = ml[2 * HS + row], l2 = ml[3 * HS + row];
  float M = fmaxf(m1, m2);
  float w1 = __expf(m1 - M), w2 = __expf(m2 - M);
  float inv = 1.0f / (l1 * w1 + l2 * w2);
  int bh = row >> 11, s = row & 2047;
  int b = bh >> 4, h = bh & 15;
  u16x4v rr;
#pragma unroll
  for (int j = 0; j < 4; ++j) rr[j] = f2bf((o1[j] * w1 + o2[j] * w2) * inv);
  *(u16x4v*)(O + ((size_t)(b * SEQ + s)) * DIMM + h * HD + d0) = rr;
}

extern "C" void kernel_launch(void* const* d_in, const int* in_sizes, int n_in,
                              void* d_out, int out_size, void* d_ws, size_t ws_size,
                              hipStream_t stream) {
  const float* x = (const float*)d_in[0];
  const float* wq = (const float*)d_in[1];
  const float* wkv = (const float*)d_in[2];
  const float* wout = (const float*)d_in[3];
  float* out = (float*)d_out;

  u16* ws = (u16*)d_ws;
  const size_t M1 = (size_t)1024 * 1024;
  u16* xh = ws;                    // 4M u16
  u16* xl = xh + 4 * M1;           // 4M
  u16* wqTh = xl + 4 * M1;         // 1M
  u16* wqTl = wqTh + M1;           // 1M
  u16* wkvTh = wqTl + M1;          // 2M
  u16* wkvTl = wkvTh + 2 * M1;     // 2M
  u16* Qb = wkvTl + 2 * M1;        // 4M
  u16* Kb = Qb + 4 * M1;           // 4M
  u16* Vb = Kb + 4 * M1;           // 4M
  // overlays (regions dead by the time they're written):
  float* Op0 = out;                // d_out as scratch: 4M f32 == 16MB exact
  float* Op1 = (float*)xh;         // xh+xl = 16MB = 4M f32
  float* mlbuf = (float*)wqTh;     // needs 1MB; wqT region = 4MB
  u16* Ob = wkvTh;                 // needs 8MB; wkvT region = 8MB
  u16* woutT = Kb;                 // needs 2MB; Kb dead after attn

  conv_x_split<<<4096, 256, 0, stream>>>(x, xh, xl);
  conv_wT_split<<<dim3(32, 32), 256, 0, stream>>>(wq, wqTh, wqTl, 1024, 1024);
  conv_wT_split<<<dim3(64, 32), 256, 0, stream>>>(wkv, wkvTh, wkvTl, 1024, 2048);

  gemm3<0><<<dim3(8, 32), 256, 0, stream>>>(xh, xl, wqTh, wqTl, Qb, nullptr,
                                            4096, 1024, 1024);
  gemm3<1><<<dim3(16, 32), 256, 0, stream>>>(xh, xl, wkvTh, wkvTl, Kb, Vb,
                                             4096, 2048, 1024);

  attn_kernel<<<dim3(32, 32), 256, 0, stream>>>(Qb, Kb, Vb, Op0, Op1, mlbuf);
  merge_kernel<<<4096, 256, 0, stream>>>(Op0, Op1, mlbuf, Ob);

  conv_wT<<<dim3(32, 32), 256, 0, stream>>>(wout, woutT, 1024, 1024);
  gemm1<<<dim3(8, 32), 256, 0, stream>>>(Ob, woutT, out, 4096, 1024, 1024);
}

// Round 9
// 213.554 us; speedup vs baseline: 1.3591x; 1.1249x over previous
//
#include <hip/hip_runtime.h>

typedef unsigned short u16;
typedef __bf16 bf16x8 __attribute__((ext_vector_type(8)));
typedef unsigned short u16x8v __attribute__((ext_vector_type(8)));
typedef unsigned short u16x4v __attribute__((ext_vector_type(4)));
typedef float f32x4 __attribute__((ext_vector_type(4)));

#define SEQ 2048
#define NH 16
#define HD 64
#define DIMM 1024

__device__ __forceinline__ u16 f2bf(float f) {
  unsigned u = __builtin_bit_cast(unsigned, f);
  u += 0x7fffu + ((u >> 16) & 1u);
  return (u16)(u >> 16);
}
__device__ __forceinline__ float bf2f(u16 b) {
  return __builtin_bit_cast(float, ((unsigned)b) << 16);
}

// ---------- split-convert x (f32 -> bf16 hi + bf16 lo) ----------
__global__ void conv_x_split(const float* __restrict__ x, u16* __restrict__ oh,
                             u16* __restrict__ ol) {
  size_t i = (size_t)blockIdx.x * 256 + threadIdx.x;
  f32x4 v = *(const f32x4*)(x + i * 4);
  u16x4v h, l;
#pragma unroll
  for (int j = 0; j < 4; ++j) {
    h[j] = f2bf(v[j]);
    l[j] = f2bf(v[j] - bf2f(h[j]));
  }
  *(u16x4v*)(oh + i * 4) = h;
  *(u16x4v*)(ol + i * 4) = l;
}

// ---------- transpose: W[K][N] f32 -> Wt[N][K] bf16 ----------
__global__ void conv_wT(const float* __restrict__ W, u16* __restrict__ Wt,
                        int Kd, int Nd) {
  __shared__ float t[32][33];
  int n0 = blockIdx.x * 32, k0 = blockIdx.y * 32;
  int c = threadIdx.x & 31, r8 = threadIdx.x >> 5;
#pragma unroll
  for (int rr = 0; rr < 32; rr += 8)
    t[r8 + rr][c] = W[(size_t)(k0 + r8 + rr) * Nd + n0 + c];
  __syncthreads();
#pragma unroll
  for (int rr = 0; rr < 32; rr += 8)
    Wt[(size_t)(n0 + r8 + rr) * Kd + k0 + c] = f2bf(t[c][r8 + rr]);
}

// ---------- 2-term split GEMM: C = Ah@Bh + Al@Bh (x fp32-accurate) ----------
// A{h,l}[M][K] bf16 row-major, Bt[N][K] bf16 row-major (B transposed).
// MODE 0: Q  -> rope in fp32, write bf16 C0 [b,h,s,d]
// MODE 1: KV -> cols<1024: rope, write K to C0; cols>=1024: write V to C1
template <int MODE>
__global__ void __launch_bounds__(256, 2)
gemm3(const u16* __restrict__ Ah, const u16* __restrict__ Al,
      const u16* __restrict__ Bth,
      u16* __restrict__ C0, u16* __restrict__ C1, int M, int N, int K) {
  __shared__ u16 AsH[128][72];
  __shared__ u16 AsL[128][72];
  __shared__ u16 BsH[128][72];
  const int tid = threadIdx.x;
  const int lane = tid & 63, wave = tid >> 6;
  const int wr = wave >> 1, wc = wave & 1;
  const int lr = lane & 15, lg = lane >> 4;
  const int bm = blockIdx.y * 128, bn = blockIdx.x * 128;

  f32x4 acc[4][4];
#pragma unroll
  for (int m = 0; m < 4; ++m)
#pragma unroll
    for (int n = 0; n < 4; ++n) acc[m][n] = (f32x4){0.f, 0.f, 0.f, 0.f};

  for (int k0 = 0; k0 < K; k0 += 64) {
    __syncthreads();
#pragma unroll
    for (int it = 0; it < 4; ++it) {
      int id = it * 256 + tid;
      int row = id >> 3, c8 = (id & 7) * 8;
      size_t aoff = (size_t)(bm + row) * K + k0 + c8;
      size_t boff = (size_t)(bn + row) * K + k0 + c8;
      *(u16x8v*)&AsH[row][c8] = *(const u16x8v*)(Ah + aoff);
      *(u16x8v*)&AsL[row][c8] = *(const u16x8v*)(Al + aoff);
      *(u16x8v*)&BsH[row][c8] = *(const u16x8v*)(Bth + boff);
    }
    __syncthreads();
#pragma unroll
    for (int kk = 0; kk < 2; ++kk) {
      bf16x8 afh[4], afl[4], bfh[4];
#pragma unroll
      for (int m = 0; m < 4; ++m) {
        afh[m] = *(const bf16x8*)&AsH[wr * 64 + m * 16 + lr][kk * 32 + lg * 8];
        afl[m] = *(const bf16x8*)&AsL[wr * 64 + m * 16 + lr][kk * 32 + lg * 8];
      }
#pragma unroll
      for (int n = 0; n < 4; ++n)
        bfh[n] = *(const bf16x8*)&BsH[wc * 64 + n * 16 + lr][kk * 32 + lg * 8];
#pragma unroll
      for (int m = 0; m < 4; ++m)
#pragma unroll
        for (int n = 0; n < 4; ++n) {
          acc[m][n] = __builtin_amdgcn_mfma_f32_16x16x32_bf16(afh[m], bfh[n],
                                                              acc[m][n], 0, 0, 0);
          acc[m][n] = __builtin_amdgcn_mfma_f32_16x16x32_bf16(afl[m], bfh[n],
                                                              acc[m][n], 0, 0, 0);
        }
    }
  }

  // fp32 RoPE on rotary dims (d<32 == fragments n=0,n=1)
  const bool doRope = (MODE == 0) || (MODE == 1 && bn < 1024);
  if (doRope) {
    float inv = __expf(-(float)lr * 0.5756462732485115f);  // ln(10000)/16
#pragma unroll
    for (int m = 0; m < 4; ++m) {
#pragma unroll
      for (int r = 0; r < 4; ++r) {
        int row = bm + wr * 64 + m * 16 + 4 * lg + r;
        int s = row & (SEQ - 1);
        float ang = (float)s * inv;
        float sn, cs;
        __sincosf(ang, &sn, &cs);
        float x1 = acc[m][0][r], x2 = acc[m][1][r];
        acc[m][0][r] = x1 * cs - x2 * sn;
        acc[m][1][r] = x2 * cs + x1 * sn;
      }
    }
  }

#pragma unroll
  for (int m = 0; m < 4; ++m) {
#pragma unroll
    for (int n = 0; n < 4; ++n) {
#pragma unroll
      for (int r = 0; r < 4; ++r) {
        int row = bm + wr * 64 + m * 16 + 4 * lg + r;
        int col = bn + wc * 64 + n * 16 + lr;
        float v = acc[m][n][r];
        if (MODE == 0) {
          int b = row >> 11, s = row & 2047, h = col >> 6, d = col & 63;
          C0[(((size_t)(b * NH + h)) * SEQ + s) * HD + d] = f2bf(v);
        } else {
          int b = row >> 11, s = row & 2047;
          int cc = col;
          u16* dst = C0;
          if (cc >= 1024) { cc -= 1024; dst = C1; }
          int h = cc >> 6, d = cc & 63;
          dst[(((size_t)(b * NH + h)) * SEQ + s) * HD + d] = f2bf(v);
        }
      }
    }
  }
}

// ---------- single-term GEMM for output projection ----------
__global__ void __launch_bounds__(256, 2)
gemm1(const u16* __restrict__ A, const u16* __restrict__ Bt,
      float* __restrict__ CF, int M, int N, int K) {
  __shared__ u16 As[128][72];
  __shared__ u16 Bs[128][72];
  const int tid = threadIdx.x;
  const int lane = tid & 63, wave = tid >> 6;
  const int wr = wave >> 1, wc = wave & 1;
  const int lr = lane & 15, lg = lane >> 4;
  const int bm = blockIdx.y * 128, bn = blockIdx.x * 128;

  f32x4 acc[4][4];
#pragma unroll
  for (int m = 0; m < 4; ++m)
#pragma unroll
    for (int n = 0; n < 4; ++n) acc[m][n] = (f32x4){0.f, 0.f, 0.f, 0.f};

  for (int k0 = 0; k0 < K; k0 += 64) {
    __syncthreads();
#pragma unroll
    for (int it = 0; it < 2; ++it) {
      int id = it * 512 + tid * 2;
      int row = id >> 3, c8 = (id & 6) * 8;
      size_t aoff = (size_t)(bm + row) * K + k0 + c8;
      size_t boff = (size_t)(bn + row) * K + k0 + c8;
      *(u16x8v*)&As[row][c8] = *(const u16x8v*)(A + aoff);
      *(u16x8v*)&As[row][c8 + 8] = *(const u16x8v*)(A + aoff + 8);
      *(u16x8v*)&Bs[row][c8] = *(const u16x8v*)(Bt + boff);
      *(u16x8v*)&Bs[row][c8 + 8] = *(const u16x8v*)(Bt + boff + 8);
    }
    __syncthreads();
#pragma unroll
    for (int kk = 0; kk < 2; ++kk) {
      bf16x8 af[4], bfr[4];
#pragma unroll
      for (int m = 0; m < 4; ++m)
        af[m] = *(const bf16x8*)&As[wr * 64 + m * 16 + lr][kk * 32 + lg * 8];
#pragma unroll
      for (int n = 0; n < 4; ++n)
        bfr[n] = *(const bf16x8*)&Bs[wc * 64 + n * 16 + lr][kk * 32 + lg * 8];
#pragma unroll
      for (int m = 0; m < 4; ++m)
#pragma unroll
        for (int n = 0; n < 4; ++n)
          acc[m][n] = __builtin_amdgcn_mfma_f32_16x16x32_bf16(af[m], bfr[n],
                                                              acc[m][n], 0, 0, 0);
    }
  }

#pragma unroll
  for (int m = 0; m < 4; ++m)
#pragma unroll
    for (int n = 0; n < 4; ++n)
#pragma unroll
      for (int r = 0; r < 4; ++r) {
        int row = bm + wr * 64 + m * 16 + 4 * lg + r;
        int col = bn + wc * 64 + n * 16 + lr;
        CF[(size_t)row * N + col] = acc[m][n][r];
      }
}

// ---------- flash attention, KV-split x2 + causal pairing ----------
__global__ void __launch_bounds__(256, 2)
attn_kernel(const u16* __restrict__ Q, const u16* __restrict__ K,
            const u16* __restrict__ V, float* __restrict__ Op0,
            float* __restrict__ Op1, float* __restrict__ ml) {
  __shared__ u16 Ks[64][72];
  __shared__ u16 Vt[64][72];      // Vt[d][kv]
  __shared__ u16 Ps[4][16][72];   // per-wave P tile
  const int tid = threadIdx.x, lane = tid & 63, wave = tid >> 6;
  const int lr = lane & 15, lg = lane >> 4;
  const int bh = blockIdx.y;
  const size_t kvbase = (size_t)bh * SEQ * HD;

#pragma unroll 1
  for (int phase = 0; phase < 2; ++phase) {
    const int qt = phase == 0 ? (int)blockIdx.x : 31 - (int)blockIdx.x;
    const int ktmid = (qt + 2) >> 1;
    const int ktbegin = phase == 0 ? 0 : ktmid;
    const int ktend = phase == 0 ? ktmid : qt + 1;
    float* __restrict__ Opart = phase == 0 ? Op0 : Op1;
    float* __restrict__ mdst = ml + phase * (32 * SEQ);
    float* __restrict__ ldst = ml + 2 * 32 * SEQ + phase * (32 * SEQ);

    const u16* qrow_p = Q + kvbase + (size_t)(qt * 64 + wave * 16 + lr) * HD;
    bf16x8 qf[2];
    qf[0] = *(const bf16x8*)(qrow_p + lg * 8);
    qf[1] = *(const bf16x8*)(qrow_p + lg * 8 + 32);

    f32x4 oacc[4];
#pragma unroll
    for (int td = 0; td < 4; ++td) oacc[td] = (f32x4){0.f, 0.f, 0.f, 0.f};
    float mreg[4], lreg[4];
#pragma unroll
    for (int r = 0; r < 4; ++r) { mreg[r] = -1e30f; lreg[r] = 0.f; }

#pragma unroll 1
    for (int kt = ktbegin; kt < ktend; ++kt) {
      __syncthreads();
#pragma unroll
      for (int it = 0; it < 2; ++it) {
        int id = it * 256 + tid;
        int r = id >> 3, c8 = (id & 7) * 8;
        *(u16x8v*)&Ks[r][c8] =
            *(const u16x8v*)(K + kvbase + (size_t)(kt * 64 + r) * HD + c8);
      }
#pragma unroll
      for (int it = 0; it < 2; ++it) {
        int id = it * 256 + tid;
        int r = id & 63, c8 = (id >> 6) * 8;
        u16x8v v = *(const u16x8v*)(V + kvbase + (size_t)(kt * 64 + r) * HD + c8);
#pragma unroll
        for (int j = 0; j < 8; ++j) Vt[c8 + j][r] = v[j];
      }
      __syncthreads();

      f32x4 sf[4];
      __builtin_amdgcn_s_setprio(1);
#pragma unroll
      for (int tj = 0; tj < 4; ++tj) {
        f32x4 sacc = (f32x4){0.f, 0.f, 0.f, 0.f};
        bf16x8 kf0 = *(const bf16x8*)&Ks[tj * 16 + lr][lg * 8];
        bf16x8 kf1 = *(const bf16x8*)&Ks[tj * 16 + lr][lg * 8 + 32];
        sacc = __builtin_amdgcn_mfma_f32_16x16x32_bf16(qf[0], kf0, sacc, 0, 0, 0);
        sacc = __builtin_amdgcn_mfma_f32_16x16x32_bf16(qf[1], kf1, sacc, 0, 0, 0);
        sf[tj] = sacc * 0.125f;
      }
      __builtin_amdgcn_s_setprio(0);
      if (kt == qt) {
#pragma unroll
        for (int tj = 0; tj < 4; ++tj)
#pragma unroll
          for (int r = 0; r < 4; ++r)
            if (tj * 16 + lr > wave * 16 + 4 * lg + r) sf[tj][r] = -1e30f;
      }

      // row maxima (per-row stats live in 16-lane groups)
      float mx[4];
#pragma unroll
      for (int r = 0; r < 4; ++r) {
        float m0 = fmaxf(fmaxf(sf[0][r], sf[1][r]), fmaxf(sf[2][r], sf[3][r]));
#pragma unroll
        for (int off = 1; off < 16; off <<= 1) m0 = fmaxf(m0, __shfl_xor(m0, off));
        mx[r] = m0;
      }
      // defer-max (THR=8): skip rescale when all wave rows grew little
      bool defer = __all((mx[0] - mreg[0] <= 8.f) && (mx[1] - mreg[1] <= 8.f) &&
                         (mx[2] - mreg[2] <= 8.f) && (mx[3] - mreg[3] <= 8.f));
      if (!defer) {
#pragma unroll
        for (int r = 0; r < 4; ++r) {
          float mn = fmaxf(mreg[r], mx[r]);
          float fac = __expf(mreg[r] - mn);
          mreg[r] = mn;
          lreg[r] *= fac;
#pragma unroll
          for (int td = 0; td < 4; ++td) oacc[td][r] *= fac;
        }
      }
#pragma unroll
      for (int r = 0; r < 4; ++r) {
        float rsum = 0.f;
#pragma unroll
        for (int tj = 0; tj < 4; ++tj) {
          float p = __expf(sf[tj][r] - mreg[r]);
          sf[tj][r] = p;
          rsum += p;
        }
#pragma unroll
        for (int off = 1; off < 16; off <<= 1) rsum += __shfl_xor(rsum, off);
        lreg[r] += rsum;
      }
#pragma unroll
      for (int tj = 0; tj < 4; ++tj)
#pragma unroll
        for (int r = 0; r < 4; ++r)
          Ps[wave][4 * lg + r][tj * 16 + lr] = f2bf(sf[tj][r]);
      // no barrier: Ps is wave-private; Vt synced at loop head
      __builtin_amdgcn_s_setprio(1);
#pragma unroll
      for (int c = 0; c < 2; ++c) {
        bf16x8 pf = *(const bf16x8*)&Ps[wave][lr][c * 32 + lg * 8];
#pragma unroll
        for (int td = 0; td < 4; ++td) {
          bf16x8 vf = *(const bf16x8*)&Vt[td * 16 + lr][c * 32 + lg * 8];
          oacc[td] = __builtin_amdgcn_mfma_f32_16x16x32_bf16(pf, vf, oacc[td], 0, 0, 0);
        }
      }
      __builtin_amdgcn_s_setprio(0);
    }

    // partial epilogue: premultiplied O (f32) + m/l
#pragma unroll
    for (int r = 0; r < 4; ++r) {
      int s = qt * 64 + wave * 16 + 4 * lg + r;
      size_t rowb = kvbase + (size_t)s * HD;  // Opart is [32][SEQ][64]
#pragma unroll
      for (int td = 0; td < 4; ++td) Opart[rowb + td * 16 + lr] = oacc[td][r];
      if (lr == 0) {
        mdst[bh * SEQ + s] = mreg[r];
        ldst[bh * SEQ + s] = lreg[r];
      }
    }
  }
}

// ---------- merge the two KV-half partials, write bf16 O [b,s,h*64+d] ----------
__global__ void merge_kernel(const float* __restrict__ Op0,
                             const float* __restrict__ Op1,
                             const float* __restrict__ ml,
                             u16* __restrict__ O) {
  int i = blockIdx.x * 256 + threadIdx.x;
  int row = i >> 4;  // bh*SEQ + s
  int d0 = (i & 15) * 4;
  size_t base = (size_t)row * 64 + d0;
  f32x4 o1 = *(const f32x4*)(Op0 + base);
  f32x4 o2 = *(const f32x4*)(Op1 + base);
  const int HS = 32 * SEQ;
  float m1 = ml[row], m2 = ml[HS + row];
  float l1 = ml[2 * HS + row], l2 = ml[3 * HS + row];
  float M = fmaxf(m1, m2);
  float w1 = __expf(m1 - M), w2 = __expf(m2 - M);
  float inv = 1.0f / (l1 * w1 + l2 * w2);
  int bh = row >> 11, s = row & 2047;
  int b = bh >> 4, h = bh & 15;
  u16x4v rr;
#pragma unroll
  for (int j = 0; j < 4; ++j) rr[j] = f2bf((o1[j] * w1 + o2[j] * w2) * inv);
  *(u16x4v*)(O + ((size_t)(b * SEQ + s)) * DIMM + h * HD + d0) = rr;
}

extern "C" void kernel_launch(void* const* d_in, const int* in_sizes, int n_in,
                              void* d_out, int out_size, void* d_ws, size_t ws_size,
                              hipStream_t stream) {
  const float* x = (const float*)d_in[0];
  const float* wq = (const float*)d_in[1];
  const float* wkv = (const float*)d_in[2];
  const float* wout = (const float*)d_in[3];
  float* out = (float*)d_out;

  u16* ws = (u16*)d_ws;
  const size_t M1 = (size_t)1024 * 1024;
  u16* xh = ws;                    // 4M u16
  u16* xl = xh + 4 * M1;           // 4M
  u16* wqTh = xl + 4 * M1;         // 1M
  u16* wkvTh = wqTh + M1;          // 2M
  u16* Qb = wkvTh + 2 * M1;        // 4M
  u16* Kb = Qb + 4 * M1;           // 4M
  u16* Vb = Kb + 4 * M1;           // 4M
  // overlays (regions dead by the time they're written):
  float* Op0 = out;                // d_out as scratch: 4M f32 = 16MB exact
  float* Op1 = (float*)xh;         // xh+xl = 16MB
  float* mlbuf = (float*)wqTh;     // needs 1MB; wqTh region = 2MB
  u16* Ob = Qb;                    // needs 8MB; Qb dead after attn
  u16* woutT = Kb;                 // needs 2MB; Kb dead after attn

  conv_x_split<<<4096, 256, 0, stream>>>(x, xh, xl);
  conv_wT<<<dim3(32, 32), 256, 0, stream>>>(wq, wqTh, 1024, 1024);
  conv_wT<<<dim3(64, 32), 256, 0, stream>>>(wkv, wkvTh, 1024, 2048);

  gemm3<0><<<dim3(8, 32), 256, 0, stream>>>(xh, xl, wqTh, Qb, nullptr,
                                            4096, 1024, 1024);
  gemm3<1><<<dim3(16, 32), 256, 0, stream>>>(xh, xl, wkvTh, Kb, Vb,
                                             4096, 2048, 1024);

  attn_kernel<<<dim3(32, 32), 256, 0, stream>>>(Qb, Kb, Vb, Op0, Op1, mlbuf);
  merge_kernel<<<4096, 256, 0, stream>>>(Op0, Op1, mlbuf, Ob);

  conv_wT<<<dim3(32, 32), 256, 0, stream>>>(wout, woutT, 1024, 1024);
  gemm1<<<dim3(8, 32), 256, 0, stream>>>(Ob, woutT, out, 4096, 1024, 1024);
}

// Round 10
// 198.401 us; speedup vs baseline: 1.4629x; 1.0764x over previous
//
#include <hip/hip_runtime.h>

typedef unsigned short u16;
typedef __bf16 bf16x8 __attribute__((ext_vector_type(8)));
typedef unsigned short u16x8v __attribute__((ext_vector_type(8)));
typedef unsigned short u16x4v __attribute__((ext_vector_type(4)));
typedef float f32x4 __attribute__((ext_vector_type(4)));

#define SEQ 2048
#define NH 16
#define HD 64
#define DIMM 1024

__device__ __forceinline__ u16 f2bf(float f) {
  unsigned u = __builtin_bit_cast(unsigned, f);
  u += 0x7fffu + ((u >> 16) & 1u);
  return (u16)(u >> 16);
}
__device__ __forceinline__ float bf2f(u16 b) {
  return __builtin_bit_cast(float, ((unsigned)b) << 16);
}

// async global->LDS, 16B per lane; LDS dest = wave-uniform base + lane*16
__device__ __forceinline__ void gload16(const u16* g, u16* l) {
  __builtin_amdgcn_global_load_lds(
      (const __attribute__((address_space(1))) unsigned int*)g,
      (__attribute__((address_space(3))) unsigned int*)l, 16, 0, 0);
}

// ---------- split-convert x (f32 -> bf16 hi + bf16 lo) ----------
__global__ void conv_x_split(const float* __restrict__ x, u16* __restrict__ oh,
                             u16* __restrict__ ol) {
  size_t i = (size_t)blockIdx.x * 256 + threadIdx.x;
  f32x4 v = *(const f32x4*)(x + i * 4);
  u16x4v h, l;
#pragma unroll
  for (int j = 0; j < 4; ++j) {
    h[j] = f2bf(v[j]);
    l[j] = f2bf(v[j] - bf2f(h[j]));
  }
  *(u16x4v*)(oh + i * 4) = h;
  *(u16x4v*)(ol + i * 4) = l;
}

// ---------- transpose: W[K][N] f32 -> Wt[N][K] bf16 ----------
__global__ void conv_wT(const float* __restrict__ W, u16* __restrict__ Wt,
                        int Kd, int Nd) {
  __shared__ float t[32][33];
  int n0 = blockIdx.x * 32, k0 = blockIdx.y * 32;
  int c = threadIdx.x & 31, r8 = threadIdx.x >> 5;
#pragma unroll
  for (int rr = 0; rr < 32; rr += 8)
    t[r8 + rr][c] = W[(size_t)(k0 + r8 + rr) * Nd + n0 + c];
  __syncthreads();
#pragma unroll
  for (int rr = 0; rr < 32; rr += 8)
    Wt[(size_t)(n0 + r8 + rr) * Kd + k0 + c] = f2bf(t[c][r8 + rr]);
}

// ---------- 2-term split GEMM: C = Ah@Bh + Al@Bh (m97-style gload_lds) ------
// MODE 0: Q  -> rope in fp32, write bf16 C0 [b,h,s,d]
// MODE 1: KV -> cols<1024: rope, write K to C0; cols>=1024: write V to C1
template <int MODE>
__global__ void __launch_bounds__(256, 2)
gemm3(const u16* __restrict__ Ah, const u16* __restrict__ Al,
      const u16* __restrict__ Bth,
      u16* __restrict__ C0, u16* __restrict__ C1, int M, int N, int K) {
  __shared__ u16 AsH[128][64];
  __shared__ u16 AsL[128][64];
  __shared__ u16 BsH[128][64];
  const int tid = threadIdx.x;
  const int lane = tid & 63, wave = tid >> 6;
  const int wr = wave >> 1, wc = wave & 1;
  const int lr = lane & 15, lg = lane >> 4;
  const int bm = blockIdx.y * 128, bn = blockIdx.x * 128;
  const int lrow = lane >> 3;         // 0..7
  const int lcol8 = (lane & 7) * 8;   // u16 column of this lane's 16B chunk

  f32x4 acc[4][4];
#pragma unroll
  for (int m = 0; m < 4; ++m)
#pragma unroll
    for (int n = 0; n < 4; ++n) acc[m][n] = (f32x4){0.f, 0.f, 0.f, 0.f};

  for (int k0 = 0; k0 < K; k0 += 64) {
    __syncthreads();
    // wave stages rows [wave*32, wave*32+32) of each stream: 4 calls x 8 rows
#pragma unroll
    for (int c = 0; c < 4; ++c) {
      int r0 = wave * 32 + c * 8;
      size_t arow = (size_t)(bm + r0 + lrow) * K + k0 + lcol8;
      size_t brow = (size_t)(bn + r0 + lrow) * K + k0 + lcol8;
      gload16(Ah + arow, &AsH[r0][0]);
      gload16(Al + arow, &AsL[r0][0]);
      gload16(Bth + brow, &BsH[r0][0]);
    }
    __syncthreads();  // drains vmcnt -> staged data visible
#pragma unroll
    for (int kk = 0; kk < 2; ++kk) {
      bf16x8 afh[4], afl[4], bfh[4];
#pragma unroll
      for (int m = 0; m < 4; ++m) {
        afh[m] = *(const bf16x8*)&AsH[wr * 64 + m * 16 + lr][kk * 32 + lg * 8];
        afl[m] = *(const bf16x8*)&AsL[wr * 64 + m * 16 + lr][kk * 32 + lg * 8];
      }
#pragma unroll
      for (int n = 0; n < 4; ++n)
        bfh[n] = *(const bf16x8*)&BsH[wc * 64 + n * 16 + lr][kk * 32 + lg * 8];
#pragma unroll
      for (int m = 0; m < 4; ++m)
#pragma unroll
        for (int n = 0; n < 4; ++n) {
          acc[m][n] = __builtin_amdgcn_mfma_f32_16x16x32_bf16(afh[m], bfh[n],
                                                              acc[m][n], 0, 0, 0);
          acc[m][n] = __builtin_amdgcn_mfma_f32_16x16x32_bf16(afl[m], bfh[n],
                                                              acc[m][n], 0, 0, 0);
        }
    }
  }

  // fp32 RoPE on rotary dims (d<32 == fragments n=0,n=1)
  const bool doRope = (MODE == 0) || (MODE == 1 && bn < 1024);
  if (doRope) {
    float inv = __expf(-(float)lr * 0.5756462732485115f);  // ln(10000)/16
#pragma unroll
    for (int m = 0; m < 4; ++m) {
#pragma unroll
      for (int r = 0; r < 4; ++r) {
        int row = bm + wr * 64 + m * 16 + 4 * lg + r;
        int s = row & (SEQ - 1);
        float ang = (float)s * inv;
        float sn, cs;
        __sincosf(ang, &sn, &cs);
        float x1 = acc[m][0][r], x2 = acc[m][1][r];
        acc[m][0][r] = x1 * cs - x2 * sn;
        acc[m][1][r] = x2 * cs + x1 * sn;
      }
    }
  }

#pragma unroll
  for (int m = 0; m < 4; ++m) {
#pragma unroll
    for (int n = 0; n < 4; ++n) {
#pragma unroll
      for (int r = 0; r < 4; ++r) {
        int row = bm + wr * 64 + m * 16 + 4 * lg + r;
        int col = bn + wc * 64 + n * 16 + lr;
        float v = acc[m][n][r];
        if (MODE == 0) {
          int b = row >> 11, s = row & 2047, h = col >> 6, d = col & 63;
          C0[(((size_t)(b * NH + h)) * SEQ + s) * HD + d] = f2bf(v);
        } else {
          int b = row >> 11, s = row & 2047;
          int cc = col;
          u16* dst = C0;
          if (cc >= 1024) { cc -= 1024; dst = C1; }
          int h = cc >> 6, d = cc & 63;
          dst[(((size_t)(b * NH + h)) * SEQ + s) * HD + d] = f2bf(v);
        }
      }
    }
  }
}

// ---------- single-term GEMM for output projection (gload_lds staging) ------
__global__ void __launch_bounds__(256, 2)
gemm1(const u16* __restrict__ A, const u16* __restrict__ Bt,
      float* __restrict__ CF, int M, int N, int K) {
  __shared__ u16 As[128][64];
  __shared__ u16 Bs[128][64];
  const int tid = threadIdx.x;
  const int lane = tid & 63, wave = tid >> 6;
  const int wr = wave >> 1, wc = wave & 1;
  const int lr = lane & 15, lg = lane >> 4;
  const int bm = blockIdx.y * 128, bn = blockIdx.x * 128;
  const int lrow = lane >> 3;
  const int lcol8 = (lane & 7) * 8;

  f32x4 acc[4][4];
#pragma unroll
  for (int m = 0; m < 4; ++m)
#pragma unroll
    for (int n = 0; n < 4; ++n) acc[m][n] = (f32x4){0.f, 0.f, 0.f, 0.f};

  for (int k0 = 0; k0 < K; k0 += 64) {
    __syncthreads();
#pragma unroll
    for (int c = 0; c < 4; ++c) {
      int r0 = wave * 32 + c * 8;
      size_t arow = (size_t)(bm + r0 + lrow) * K + k0 + lcol8;
      size_t brow = (size_t)(bn + r0 + lrow) * K + k0 + lcol8;
      gload16(A + arow, &As[r0][0]);
      gload16(Bt + brow, &Bs[r0][0]);
    }
    __syncthreads();
#pragma unroll
    for (int kk = 0; kk < 2; ++kk) {
      bf16x8 af[4], bfr[4];
#pragma unroll
      for (int m = 0; m < 4; ++m)
        af[m] = *(const bf16x8*)&As[wr * 64 + m * 16 + lr][kk * 32 + lg * 8];
#pragma unroll
      for (int n = 0; n < 4; ++n)
        bfr[n] = *(const bf16x8*)&Bs[wc * 64 + n * 16 + lr][kk * 32 + lg * 8];
#pragma unroll
      for (int m = 0; m < 4; ++m)
#pragma unroll
        for (int n = 0; n < 4; ++n)
          acc[m][n] = __builtin_amdgcn_mfma_f32_16x16x32_bf16(af[m], bfr[n],
                                                              acc[m][n], 0, 0, 0);
    }
  }

#pragma unroll
  for (int m = 0; m < 4; ++m)
#pragma unroll
    for (int n = 0; n < 4; ++n)
#pragma unroll
      for (int r = 0; r < 4; ++r) {
        int row = bm + wr * 64 + m * 16 + 4 * lg + r;
        int col = bn + wc * 64 + n * 16 + lr;
        CF[(size_t)row * N + col] = acc[m][n][r];
      }
}

// ---------- flash attention, KV-split x2 + causal pairing (unchanged) -------
__global__ void __launch_bounds__(256, 2)
attn_kernel(const u16* __restrict__ Q, const u16* __restrict__ K,
            const u16* __restrict__ V, float* __restrict__ Op0,
            float* __restrict__ Op1, float* __restrict__ ml) {
  __shared__ u16 Ks[64][72];
  __shared__ u16 Vt[64][72];      // Vt[d][kv]
  __shared__ u16 Ps[4][16][72];   // per-wave P tile
  const int tid = threadIdx.x, lane = tid & 63, wave = tid >> 6;
  const int lr = lane & 15, lg = lane >> 4;
  const int bh = blockIdx.y;
  const size_t kvbase = (size_t)bh * SEQ * HD;

#pragma unroll 1
  for (int phase = 0; phase < 2; ++phase) {
    const int qt = phase == 0 ? (int)blockIdx.x : 31 - (int)blockIdx.x;
    const int ktmid = (qt + 2) >> 1;
    const int ktbegin = phase == 0 ? 0 : ktmid;
    const int ktend = phase == 0 ? ktmid : qt + 1;
    float* __restrict__ Opart = phase == 0 ? Op0 : Op1;
    float* __restrict__ mdst = ml + phase * (32 * SEQ);
    float* __restrict__ ldst = ml + 2 * 32 * SEQ + phase * (32 * SEQ);

    const u16* qrow_p = Q + kvbase + (size_t)(qt * 64 + wave * 16 + lr) * HD;
    bf16x8 qf[2];
    qf[0] = *(const bf16x8*)(qrow_p + lg * 8);
    qf[1] = *(const bf16x8*)(qrow_p + lg * 8 + 32);

    f32x4 oacc[4];
#pragma unroll
    for (int td = 0; td < 4; ++td) oacc[td] = (f32x4){0.f, 0.f, 0.f, 0.f};
    float mreg[4], lreg[4];
#pragma unroll
    for (int r = 0; r < 4; ++r) { mreg[r] = -1e30f; lreg[r] = 0.f; }

#pragma unroll 1
    for (int kt = ktbegin; kt < ktend; ++kt) {
      __syncthreads();
#pragma unroll
      for (int it = 0; it < 2; ++it) {
        int id = it * 256 + tid;
        int r = id >> 3, c8 = (id & 7) * 8;
        *(u16x8v*)&Ks[r][c8] =
            *(const u16x8v*)(K + kvbase + (size_t)(kt * 64 + r) * HD + c8);
      }
#pragma unroll
      for (int it = 0; it < 2; ++it) {
        int id = it * 256 + tid;
        int r = id & 63, c8 = (id >> 6) * 8;
        u16x8v v = *(const u16x8v*)(V + kvbase + (size_t)(kt * 64 + r) * HD + c8);
#pragma unroll
        for (int j = 0; j < 8; ++j) Vt[c8 + j][r] = v[j];
      }
      __syncthreads();

      f32x4 sf[4];
      __builtin_amdgcn_s_setprio(1);
#pragma unroll
      for (int tj = 0; tj < 4; ++tj) {
        f32x4 sacc = (f32x4){0.f, 0.f, 0.f, 0.f};
        bf16x8 kf0 = *(const bf16x8*)&Ks[tj * 16 + lr][lg * 8];
        bf16x8 kf1 = *(const bf16x8*)&Ks[tj * 16 + lr][lg * 8 + 32];
        sacc = __builtin_amdgcn_mfma_f32_16x16x32_bf16(qf[0], kf0, sacc, 0, 0, 0);
        sacc = __builtin_amdgcn_mfma_f32_16x16x32_bf16(qf[1], kf1, sacc, 0, 0, 0);
        sf[tj] = sacc * 0.125f;
      }
      __builtin_amdgcn_s_setprio(0);
      if (kt == qt) {
#pragma unroll
        for (int tj = 0; tj < 4; ++tj)
#pragma unroll
          for (int r = 0; r < 4; ++r)
            if (tj * 16 + lr > wave * 16 + 4 * lg + r) sf[tj][r] = -1e30f;
      }

      float mx[4];
#pragma unroll
      for (int r = 0; r < 4; ++r) {
        float m0 = fmaxf(fmaxf(sf[0][r], sf[1][r]), fmaxf(sf[2][r], sf[3][r]));
#pragma unroll
        for (int off = 1; off < 16; off <<= 1) m0 = fmaxf(m0, __shfl_xor(m0, off));
        mx[r] = m0;
      }
      bool defer = __all((mx[0] - mreg[0] <= 8.f) && (mx[1] - mreg[1] <= 8.f) &&
                         (mx[2] - mreg[2] <= 8.f) && (mx[3] - mreg[3] <= 8.f));
      if (!defer) {
#pragma unroll
        for (int r = 0; r < 4; ++r) {
          float mn = fmaxf(mreg[r], mx[r]);
          float fac = __expf(mreg[r] - mn);
          mreg[r] = mn;
          lreg[r] *= fac;
#pragma unroll
          for (int td = 0; td < 4; ++td) oacc[td][r] *= fac;
        }
      }
#pragma unroll
      for (int r = 0; r < 4; ++r) {
        float rsum = 0.f;
#pragma unroll
        for (int tj = 0; tj < 4; ++tj) {
          float p = __expf(sf[tj][r] - mreg[r]);
          sf[tj][r] = p;
          rsum += p;
        }
#pragma unroll
        for (int off = 1; off < 16; off <<= 1) rsum += __shfl_xor(rsum, off);
        lreg[r] += rsum;
      }
#pragma unroll
      for (int tj = 0; tj < 4; ++tj)
#pragma unroll
        for (int r = 0; r < 4; ++r)
          Ps[wave][4 * lg + r][tj * 16 + lr] = f2bf(sf[tj][r]);
      __builtin_amdgcn_s_setprio(1);
#pragma unroll
      for (int c = 0; c < 2; ++c) {
        bf16x8 pf = *(const bf16x8*)&Ps[wave][lr][c * 32 + lg * 8];
#pragma unroll
        for (int td = 0; td < 4; ++td) {
          bf16x8 vf = *(const bf16x8*)&Vt[td * 16 + lr][c * 32 + lg * 8];
          oacc[td] = __builtin_amdgcn_mfma_f32_16x16x32_bf16(pf, vf, oacc[td], 0, 0, 0);
        }
      }
      __builtin_amdgcn_s_setprio(0);
    }

#pragma unroll
    for (int r = 0; r < 4; ++r) {
      int s = qt * 64 + wave * 16 + 4 * lg + r;
      size_t rowb = kvbase + (size_t)s * HD;
#pragma unroll
      for (int td = 0; td < 4; ++td) Opart[rowb + td * 16 + lr] = oacc[td][r];
      if (lr == 0) {
        mdst[bh * SEQ + s] = mreg[r];
        ldst[bh * SEQ + s] = lreg[r];
      }
    }
  }
}

// ---------- merge the two KV-half partials, write bf16 O [b,s,h*64+d] ----------
__global__ void merge_kernel(const float* __restrict__ Op0,
                             const float* __restrict__ Op1,
                             const float* __restrict__ ml,
                             u16* __restrict__ O) {
  int i = blockIdx.x * 256 + threadIdx.x;
  int row = i >> 4;  // bh*SEQ + s
  int d0 = (i & 15) * 4;
  size_t base = (size_t)row * 64 + d0;
  f32x4 o1 = *(const f32x4*)(Op0 + base);
  f32x4 o2 = *(const f32x4*)(Op1 + base);
  const int HS = 32 * SEQ;
  float m1 = ml[row], m2 = ml[HS + row];
  float l1 = ml[2 * HS + row], l2 = ml[3 * HS + row];
  float M = fmaxf(m1, m2);
  float w1 = __expf(m1 - M), w2 = __expf(m2 - M);
  float inv = 1.0f / (l1 * w1 + l2 * w2);
  int bh = row >> 11, s = row & 2047;
  int b = bh >> 4, h = bh & 15;
  u16x4v rr;
#pragma unroll
  for (int j = 0; j < 4; ++j) rr[j] = f2bf((o1[j] * w1 + o2[j] * w2) * inv);
  *(u16x4v*)(O + ((size_t)(b * SEQ + s)) * DIMM + h * HD + d0) = rr;
}

extern "C" void kernel_launch(void* const* d_in, const int* in_sizes, int n_in,
                              void* d_out, int out_size, void* d_ws, size_t ws_size,
                              hipStream_t stream) {
  const float* x = (const float*)d_in[0];
  const float* wq = (const float*)d_in[1];
  const float* wkv = (const float*)d_in[2];
  const float* wout = (const float*)d_in[3];
  float* out = (float*)d_out;

  u16* ws = (u16*)d_ws;
  const size_t M1 = (size_t)1024 * 1024;
  u16* xh = ws;                    // 4M u16
  u16* xl = xh + 4 * M1;           // 4M
  u16* wqTh = xl + 4 * M1;         // 1M
  u16* wkvTh = wqTh + M1;          // 2M
  u16* Qb = wkvTh + 2 * M1;        // 4M
  u16* Kb = Qb + 4 * M1;           // 4M
  u16* Vb = Kb + 4 * M1;           // 4M
  // overlays (regions dead by the time they're written):
  float* Op0 = out;                // d_out as scratch: 4M f32 = 16MB exact
  float* Op1 = (float*)xh;         // xh+xl = 16MB
  float* mlbuf = (float*)wqTh;     // needs 1MB; wqTh region = 2MB
  u16* Ob = Qb;                    // needs 8MB; Qb dead after attn
  u16* woutT = Kb;                 // needs 2MB; Kb dead after attn

  conv_x_split<<<4096, 256, 0, stream>>>(x, xh, xl);
  conv_wT<<<dim3(32, 32), 256, 0, stream>>>(wq, wqTh, 1024, 1024);
  conv_wT<<<dim3(64, 32), 256, 0, stream>>>(wkv, wkvTh, 1024, 2048);

  gemm3<0><<<dim3(8, 32), 256, 0, stream>>>(xh, xl, wqTh, Qb, nullptr,
                                            4096, 1024, 1024);
  gemm3<1><<<dim3(16, 32), 256, 0, stream>>>(xh, xl, wkvTh, Kb, Vb,
                                             4096, 2048, 1024);

  attn_kernel<<<dim3(32, 32), 256, 0, stream>>>(Qb, Kb, Vb, Op0, Op1, mlbuf);
  merge_kernel<<<4096, 256, 0, stream>>>(Op0, Op1, mlbuf, Ob);

  conv_wT<<<dim3(32, 32), 256, 0, stream>>>(wout, woutT, 1024, 1024);
  gemm1<<<dim3(8, 32), 256, 0, stream>>>(Ob, woutT, out, 4096, 1024, 1024);
}

// Round 11
// 170.617 us; speedup vs baseline: 1.7011x; 1.1628x over previous
//
#include <hip/hip_runtime.h>

typedef unsigned short u16;
typedef __bf16 bf16x8 __attribute__((ext_vector_type(8)));
typedef unsigned short u16x8v __attribute__((ext_vector_type(8)));
typedef unsigned short u16x4v __attribute__((ext_vector_type(4)));
typedef float f32x4 __attribute__((ext_vector_type(4)));

#define SEQ 2048
#define NH 16
#define HD 64
#define DIMM 1024

__device__ __forceinline__ u16 f2bf(float f) {
  unsigned u = __builtin_bit_cast(unsigned, f);
  u += 0x7fffu + ((u >> 16) & 1u);
  return (u16)(u >> 16);
}
__device__ __forceinline__ float bf2f(u16 b) {
  return __builtin_bit_cast(float, ((unsigned)b) << 16);
}

// async global->LDS, 16B per lane; LDS dest = wave-uniform base + lane*16
__device__ __forceinline__ void gload16(const u16* g, u16* l) {
  __builtin_amdgcn_global_load_lds(
      (const __attribute__((address_space(1))) unsigned int*)g,
      (__attribute__((address_space(3))) unsigned int*)l, 16, 0, 0);
}

// ---------- split-convert x (f32 -> bf16 hi + bf16 lo) ----------
__global__ void conv_x_split(const float* __restrict__ x, u16* __restrict__ oh,
                             u16* __restrict__ ol) {
  size_t i = (size_t)blockIdx.x * 256 + threadIdx.x;
  f32x4 v = *(const f32x4*)(x + i * 4);
  u16x4v h, l;
#pragma unroll
  for (int j = 0; j < 4; ++j) {
    h[j] = f2bf(v[j]);
    l[j] = f2bf(v[j] - bf2f(h[j]));
  }
  *(u16x4v*)(oh + i * 4) = h;
  *(u16x4v*)(ol + i * 4) = l;
}

// ---------- transpose: W[K][N] f32 -> Wt[N][K] bf16 ----------
__global__ void conv_wT(const float* __restrict__ W, u16* __restrict__ Wt,
                        int Kd, int Nd) {
  __shared__ float t[32][33];
  int n0 = blockIdx.x * 32, k0 = blockIdx.y * 32;
  int c = threadIdx.x & 31, r8 = threadIdx.x >> 5;
#pragma unroll
  for (int rr = 0; rr < 32; rr += 8)
    t[r8 + rr][c] = W[(size_t)(k0 + r8 + rr) * Nd + n0 + c];
  __syncthreads();
#pragma unroll
  for (int rr = 0; rr < 32; rr += 8)
    Wt[(size_t)(n0 + r8 + rr) * Kd + k0 + c] = f2bf(t[c][r8 + rr]);
}

// ---------- combined QKV projection GEMM: C = Ah@Bh + Al@Bh ----------
// B = [wqT | wkvT] rows: col<1024 -> Q (rope), 1024..2047 -> K (rope), else V.
__global__ void __launch_bounds__(256, 2)
gemmQKV(const u16* __restrict__ Ah, const u16* __restrict__ Al,
        const u16* __restrict__ Bt, u16* __restrict__ Qb,
        u16* __restrict__ Kb, u16* __restrict__ Vb, int M, int N, int K) {
  __shared__ u16 AsH[128][64];
  __shared__ u16 AsL[128][64];
  __shared__ u16 BsH[128][64];
  const int tid = threadIdx.x;
  const int lane = tid & 63, wave = tid >> 6;
  const int wr = wave >> 1, wc = wave & 1;
  const int lr = lane & 15, lg = lane >> 4;
  const int bm = blockIdx.y * 128, bn = blockIdx.x * 128;
  const int lrow = lane >> 3;
  const int lcol8 = (lane & 7) * 8;

  f32x4 acc[4][4];
#pragma unroll
  for (int m = 0; m < 4; ++m)
#pragma unroll
    for (int n = 0; n < 4; ++n) acc[m][n] = (f32x4){0.f, 0.f, 0.f, 0.f};

  for (int k0 = 0; k0 < K; k0 += 64) {
    __syncthreads();
#pragma unroll
    for (int c = 0; c < 4; ++c) {
      int r0 = wave * 32 + c * 8;
      size_t arow = (size_t)(bm + r0 + lrow) * K + k0 + lcol8;
      size_t brow = (size_t)(bn + r0 + lrow) * K + k0 + lcol8;
      gload16(Ah + arow, &AsH[r0][0]);
      gload16(Al + arow, &AsL[r0][0]);
      gload16(Bt + brow, &BsH[r0][0]);
    }
    __syncthreads();
#pragma unroll
    for (int kk = 0; kk < 2; ++kk) {
      bf16x8 afh[4], afl[4], bfh[4];
#pragma unroll
      for (int m = 0; m < 4; ++m) {
        afh[m] = *(const bf16x8*)&AsH[wr * 64 + m * 16 + lr][kk * 32 + lg * 8];
        afl[m] = *(const bf16x8*)&AsL[wr * 64 + m * 16 + lr][kk * 32 + lg * 8];
      }
#pragma unroll
      for (int n = 0; n < 4; ++n)
        bfh[n] = *(const bf16x8*)&BsH[wc * 64 + n * 16 + lr][kk * 32 + lg * 8];
#pragma unroll
      for (int m = 0; m < 4; ++m)
#pragma unroll
        for (int n = 0; n < 4; ++n) {
          acc[m][n] = __builtin_amdgcn_mfma_f32_16x16x32_bf16(afh[m], bfh[n],
                                                              acc[m][n], 0, 0, 0);
          acc[m][n] = __builtin_amdgcn_mfma_f32_16x16x32_bf16(afl[m], bfh[n],
                                                              acc[m][n], 0, 0, 0);
        }
    }
  }

  const int sel = bn >> 10;  // 0=Q, 1=K, 2=V (block-uniform, tiles never straddle)
  u16* __restrict__ dst = sel == 0 ? Qb : (sel == 1 ? Kb : Vb);
  if (sel < 2) {  // fp32 RoPE on rotary dims (d<32 == fragments n=0,n=1)
    float inv = __expf(-(float)lr * 0.5756462732485115f);  // ln(10000)/16
#pragma unroll
    for (int m = 0; m < 4; ++m) {
#pragma unroll
      for (int r = 0; r < 4; ++r) {
        int row = bm + wr * 64 + m * 16 + 4 * lg + r;
        int s = row & (SEQ - 1);
        float ang = (float)s * inv;
        float sn, cs;
        __sincosf(ang, &sn, &cs);
        float x1 = acc[m][0][r], x2 = acc[m][1][r];
        acc[m][0][r] = x1 * cs - x2 * sn;
        acc[m][1][r] = x2 * cs + x1 * sn;
      }
    }
  }

#pragma unroll
  for (int m = 0; m < 4; ++m) {
#pragma unroll
    for (int n = 0; n < 4; ++n) {
#pragma unroll
      for (int r = 0; r < 4; ++r) {
        int row = bm + wr * 64 + m * 16 + 4 * lg + r;
        int col = bn + wc * 64 + n * 16 + lr;
        int b = row >> 11, s = row & 2047;
        int h = (col >> 6) & 15, d = col & 63;
        dst[(((size_t)(b * NH + h)) * SEQ + s) * HD + d] = f2bf(acc[m][n][r]);
      }
    }
  }
}

// ---------- output projection GEMM, 128x64 tiles (2 blocks/CU) ----------
__global__ void __launch_bounds__(256, 2)
gemm1(const u16* __restrict__ A, const u16* __restrict__ Bt,
      float* __restrict__ CF, int M, int N, int K) {
  __shared__ u16 As[128][64];
  __shared__ u16 Bs[64][64];
  const int tid = threadIdx.x;
  const int lane = tid & 63, wave = tid >> 6;
  const int wr = wave >> 1, wc = wave & 1;
  const int lr = lane & 15, lg = lane >> 4;
  const int bm = blockIdx.y * 128, bn = blockIdx.x * 64;
  const int lrow = lane >> 3;
  const int lcol8 = (lane & 7) * 8;

  f32x4 acc[4][2];
#pragma unroll
  for (int m = 0; m < 4; ++m)
#pragma unroll
    for (int n = 0; n < 2; ++n) acc[m][n] = (f32x4){0.f, 0.f, 0.f, 0.f};

  for (int k0 = 0; k0 < K; k0 += 64) {
    __syncthreads();
#pragma unroll
    for (int c = 0; c < 4; ++c) {
      int r0 = wave * 32 + c * 8;
      gload16(A + (size_t)(bm + r0 + lrow) * K + k0 + lcol8, &As[r0][0]);
    }
#pragma unroll
    for (int c = 0; c < 2; ++c) {
      int r0 = wave * 16 + c * 8;
      gload16(Bt + (size_t)(bn + r0 + lrow) * K + k0 + lcol8, &Bs[r0][0]);
    }
    __syncthreads();
#pragma unroll
    for (int kk = 0; kk < 2; ++kk) {
      bf16x8 af[4], bfr[2];
#pragma unroll
      for (int m = 0; m < 4; ++m)
        af[m] = *(const bf16x8*)&As[wr * 64 + m * 16 + lr][kk * 32 + lg * 8];
#pragma unroll
      for (int n = 0; n < 2; ++n)
        bfr[n] = *(const bf16x8*)&Bs[wc * 32 + n * 16 + lr][kk * 32 + lg * 8];
#pragma unroll
      for (int m = 0; m < 4; ++m)
#pragma unroll
        for (int n = 0; n < 2; ++n)
          acc[m][n] = __builtin_amdgcn_mfma_f32_16x16x32_bf16(af[m], bfr[n],
                                                              acc[m][n], 0, 0, 0);
    }
  }

#pragma unroll
  for (int m = 0; m < 4; ++m)
#pragma unroll
    for (int n = 0; n < 2; ++n)
#pragma unroll
      for (int r = 0; r < 4; ++r) {
        int row = bm + wr * 64 + m * 16 + 4 * lg + r;
        int col = bn + wc * 32 + n * 16 + lr;
        CF[(size_t)row * N + col] = acc[m][n][r];
      }
}

// ---------- flash attention, KV-split x2 + causal pairing + T14 prefetch ----
__global__ void __launch_bounds__(256, 2)
attn_kernel(const u16* __restrict__ Q, const u16* __restrict__ K,
            const u16* __restrict__ V, float* __restrict__ Op0,
            float* __restrict__ Op1, float* __restrict__ ml) {
  __shared__ u16 Ks[64][72];
  __shared__ u16 Vt[64][72];      // Vt[d][kv]
  __shared__ u16 Ps[4][16][72];   // per-wave P tile
  const int tid = threadIdx.x, lane = tid & 63, wave = tid >> 6;
  const int lr = lane & 15, lg = lane >> 4;
  const int bh = blockIdx.y;
  const size_t kvbase = (size_t)bh * SEQ * HD;
  // prefetch-staging coordinates (tid-fixed)
  const int kr0 = tid >> 3, kc0 = (tid & 7) * 8;  // K rows kr0 / kr0+32
  const int vc0 = wave * 8;                        // V cols vc0 / vc0+32, row=lane

  u16x8v kreg0, kreg1, vreg0, vreg1;

#pragma unroll 1
  for (int phase = 0; phase < 2; ++phase) {
    const int qt = phase == 0 ? (int)blockIdx.x : 31 - (int)blockIdx.x;
    const int ktmid = (qt + 2) >> 1;
    const int ktbegin = phase == 0 ? 0 : ktmid;
    const int ktend = phase == 0 ? ktmid : qt + 1;
    float* __restrict__ Opart = phase == 0 ? Op0 : Op1;
    float* __restrict__ mdst = ml + phase * (32 * SEQ);
    float* __restrict__ ldst = ml + 2 * 32 * SEQ + phase * (32 * SEQ);

    const u16* qrow_p = Q + kvbase + (size_t)(qt * 64 + wave * 16 + lr) * HD;
    bf16x8 qf[2];
    qf[0] = *(const bf16x8*)(qrow_p + lg * 8);
    qf[1] = *(const bf16x8*)(qrow_p + lg * 8 + 32);

    f32x4 oacc[4];
#pragma unroll
    for (int td = 0; td < 4; ++td) oacc[td] = (f32x4){0.f, 0.f, 0.f, 0.f};
    float mreg[4], lreg[4];
#pragma unroll
    for (int r = 0; r < 4; ++r) { mreg[r] = -1e30f; lreg[r] = 0.f; }

    // prologue prefetch of first tile
    {
      const u16* kp = K + kvbase + (size_t)(ktbegin * 64) * HD;
      const u16* vp = V + kvbase + (size_t)(ktbegin * 64) * HD;
      kreg0 = *(const u16x8v*)(kp + (size_t)kr0 * HD + kc0);
      kreg1 = *(const u16x8v*)(kp + (size_t)(kr0 + 32) * HD + kc0);
      vreg0 = *(const u16x8v*)(vp + (size_t)lane * HD + vc0);
      vreg1 = *(const u16x8v*)(vp + (size_t)lane * HD + vc0 + 32);
    }

#pragma unroll 1
    for (int kt = ktbegin; kt < ktend; ++kt) {
      __syncthreads();  // previous tile's LDS reads complete
      *(u16x8v*)&Ks[kr0][kc0] = kreg0;
      *(u16x8v*)&Ks[kr0 + 32][kc0] = kreg1;
#pragma unroll
      for (int j = 0; j < 8; ++j) Vt[vc0 + j][lane] = vreg0[j];
#pragma unroll
      for (int j = 0; j < 8; ++j) Vt[vc0 + 32 + j][lane] = vreg1[j];
      __syncthreads();
      // issue next tile's loads; they retire under this tile's compute
      if (kt + 1 < ktend) {
        const u16* kp = K + kvbase + (size_t)((kt + 1) * 64) * HD;
        const u16* vp = V + kvbase + (size_t)((kt + 1) * 64) * HD;
        kreg0 = *(const u16x8v*)(kp + (size_t)kr0 * HD + kc0);
        kreg1 = *(const u16x8v*)(kp + (size_t)(kr0 + 32) * HD + kc0);
        vreg0 = *(const u16x8v*)(vp + (size_t)lane * HD + vc0);
        vreg1 = *(const u16x8v*)(vp + (size_t)lane * HD + vc0 + 32);
      }

      f32x4 sf[4];
      __builtin_amdgcn_s_setprio(1);
#pragma unroll
      for (int tj = 0; tj < 4; ++tj) {
        f32x4 sacc = (f32x4){0.f, 0.f, 0.f, 0.f};
        bf16x8 kf0 = *(const bf16x8*)&Ks[tj * 16 + lr][lg * 8];
        bf16x8 kf1 = *(const bf16x8*)&Ks[tj * 16 + lr][lg * 8 + 32];
        sacc = __builtin_amdgcn_mfma_f32_16x16x32_bf16(qf[0], kf0, sacc, 0, 0, 0);
        sacc = __builtin_amdgcn_mfma_f32_16x16x32_bf16(qf[1], kf1, sacc, 0, 0, 0);
        sf[tj] = sacc * 0.125f;
      }
      __builtin_amdgcn_s_setprio(0);
      if (kt == qt) {
#pragma unroll
        for (int tj = 0; tj < 4; ++tj)
#pragma unroll
          for (int r = 0; r < 4; ++r)
            if (tj * 16 + lr > wave * 16 + 4 * lg + r) sf[tj][r] = -1e30f;
      }

      float mx[4];
#pragma unroll
      for (int r = 0; r < 4; ++r) {
        float m0 = fmaxf(fmaxf(sf[0][r], sf[1][r]), fmaxf(sf[2][r], sf[3][r]));
#pragma unroll
        for (int off = 1; off < 16; off <<= 1) m0 = fmaxf(m0, __shfl_xor(m0, off));
        mx[r] = m0;
      }
      bool defer = __all((mx[0] - mreg[0] <= 8.f) && (mx[1] - mreg[1] <= 8.f) &&
                         (mx[2] - mreg[2] <= 8.f) && (mx[3] - mreg[3] <= 8.f));
      if (!defer) {
#pragma unroll
        for (int r = 0; r < 4; ++r) {
          float mn = fmaxf(mreg[r], mx[r]);
          float fac = __expf(mreg[r] - mn);
          mreg[r] = mn;
          lreg[r] *= fac;
#pragma unroll
          for (int td = 0; td < 4; ++td) oacc[td][r] *= fac;
        }
      }
#pragma unroll
      for (int r = 0; r < 4; ++r) {
        float rsum = 0.f;
#pragma unroll
        for (int tj = 0; tj < 4; ++tj) {
          float p = __expf(sf[tj][r] - mreg[r]);
          sf[tj][r] = p;
          rsum += p;
        }
#pragma unroll
        for (int off = 1; off < 16; off <<= 1) rsum += __shfl_xor(rsum, off);
        lreg[r] += rsum;
      }
#pragma unroll
      for (int tj = 0; tj < 4; ++tj)
#pragma unroll
        for (int r = 0; r < 4; ++r)
          Ps[wave][4 * lg + r][tj * 16 + lr] = f2bf(sf[tj][r]);
      __builtin_amdgcn_s_setprio(1);
#pragma unroll
      for (int c = 0; c < 2; ++c) {
        bf16x8 pf = *(const bf16x8*)&Ps[wave][lr][c * 32 + lg * 8];
#pragma unroll
        for (int td = 0; td < 4; ++td) {
          bf16x8 vf = *(const bf16x8*)&Vt[td * 16 + lr][c * 32 + lg * 8];
          oacc[td] = __builtin_amdgcn_mfma_f32_16x16x32_bf16(pf, vf, oacc[td], 0, 0, 0);
        }
      }
      __builtin_amdgcn_s_setprio(0);
    }

#pragma unroll
    for (int r = 0; r < 4; ++r) {
      int s = qt * 64 + wave * 16 + 4 * lg + r;
      size_t rowb = kvbase + (size_t)s * HD;
#pragma unroll
      for (int td = 0; td < 4; ++td) Opart[rowb + td * 16 + lr] = oacc[td][r];
      if (lr == 0) {
        mdst[bh * SEQ + s] = mreg[r];
        ldst[bh * SEQ + s] = lreg[r];
      }
    }
  }
}

// ---------- merge the two KV-half partials, write bf16 O [b,s,h*64+d] ----------
__global__ void merge_kernel(const float* __restrict__ Op0,
                             const float* __restrict__ Op1,
                             const float* __restrict__ ml,
                             u16* __restrict__ O) {
  int i = blockIdx.x * 256 + threadIdx.x;
  int row = i >> 4;  // bh*SEQ + s
  int d0 = (i & 15) * 4;
  size_t base = (size_t)row * 64 + d0;
  f32x4 o1 = *(const f32x4*)(Op0 + base);
  f32x4 o2 = *(const f32x4*)(Op1 + base);
  const int HS = 32 * SEQ;
  float m1 = ml[row], m2 = ml[HS + row];
  float l1 = ml[2 * HS + row], l2 = ml[3 * HS + row];
  float M = fmaxf(m1, m2);
  float w1 = __expf(m1 - M), w2 = __expf(m2 - M);
  float inv = 1.0f / (l1 * w1 + l2 * w2);
  int bh = row >> 11, s = row & 2047;
  int b = bh >> 4, h = bh & 15;
  u16x4v rr;
#pragma unroll
  for (int j = 0; j < 4; ++j) rr[j] = f2bf((o1[j] * w1 + o2[j] * w2) * inv);
  *(u16x4v*)(O + ((size_t)(b * SEQ + s)) * DIMM + h * HD + d0) = rr;
}

extern "C" void kernel_launch(void* const* d_in, const int* in_sizes, int n_in,
                              void* d_out, int out_size, void* d_ws, size_t ws_size,
                              hipStream_t stream) {
  const float* x = (const float*)d_in[0];
  const float* wq = (const float*)d_in[1];
  const float* wkv = (const float*)d_in[2];
  const float* wout = (const float*)d_in[3];
  float* out = (float*)d_out;

  u16* ws = (u16*)d_ws;
  const size_t M1 = (size_t)1024 * 1024;
  u16* xh = ws;                    // 4M u16
  u16* xl = xh + 4 * M1;           // 4M
  u16* wqTh = xl + 4 * M1;         // 1M   (wkvTh contiguous after -> B[3072][1024])
  u16* wkvTh = wqTh + M1;          // 2M
  u16* Qb = wkvTh + 2 * M1;        // 4M
  u16* Kb = Qb + 4 * M1;           // 4M
  u16* Vb = Kb + 4 * M1;           // 4M
  // overlays (regions dead by the time they're written):
  float* Op0 = out;                // d_out as scratch: 4M f32 = 16MB exact
  float* Op1 = (float*)xh;         // xh+xl = 16MB
  float* mlbuf = (float*)wqTh;     // needs 1MB; wqTh region = 2MB
  u16* Ob = Qb;                    // needs 8MB; Qb dead after attn
  u16* woutT = Kb;                 // needs 2MB; Kb dead after attn

  conv_x_split<<<4096, 256, 0, stream>>>(x, xh, xl);
  conv_wT<<<dim3(32, 32), 256, 0, stream>>>(wq, wqTh, 1024, 1024);
  conv_wT<<<dim3(64, 32), 256, 0, stream>>>(wkv, wkvTh, 1024, 2048);

  gemmQKV<<<dim3(24, 32), 256, 0, stream>>>(xh, xl, wqTh, Qb, Kb, Vb,
                                            4096, 3072, 1024);

  attn_kernel<<<dim3(32, 32), 256, 0, stream>>>(Qb, Kb, Vb, Op0, Op1, mlbuf);
  merge_kernel<<<4096, 256, 0, stream>>>(Op0, Op1, mlbuf, Ob);

  conv_wT<<<dim3(32, 32), 256, 0, stream>>>(wout, woutT, 1024, 1024);
  gemm1<<<dim3(16, 32), 256, 0, stream>>>(Ob, woutT, out, 4096, 1024, 1024);
}

// Round 12
// 152.565 us; speedup vs baseline: 1.9024x; 1.1183x over previous
//
#include <hip/hip_runtime.h>

typedef unsigned short u16;
typedef unsigned int u32;
typedef __bf16 bf16x8 __attribute__((ext_vector_type(8)));
typedef unsigned short u16x8v __attribute__((ext_vector_type(8)));
typedef unsigned short u16x4v __attribute__((ext_vector_type(4)));
typedef unsigned int u32x4 __attribute__((ext_vector_type(4)));
typedef float f32x4 __attribute__((ext_vector_type(4)));
typedef float f32x16 __attribute__((ext_vector_type(16)));

#define SEQ 2048
#define NH 16
#define HD 64
#define DIMM 1024

__device__ __forceinline__ u16 f2bf(float f) {
  unsigned u = __builtin_bit_cast(unsigned, f);
  u += 0x7fffu + ((u >> 16) & 1u);
  return (u16)(u >> 16);
}
__device__ __forceinline__ float bf2f(u16 b) {
  return __builtin_bit_cast(float, ((unsigned)b) << 16);
}
__device__ __forceinline__ u32 pk2(float a, float b) {
  return (u32)f2bf(a) | ((u32)f2bf(b) << 16);
}

// async global->LDS, 16B per lane; LDS dest = wave-uniform base + lane*16
__device__ __forceinline__ void gload16(const u16* g, u16* l) {
  __builtin_amdgcn_global_load_lds(
      (const __attribute__((address_space(1))) unsigned int*)g,
      (__attribute__((address_space(3))) unsigned int*)l, 16, 0, 0);
}

// ---------- split-convert x (f32 -> bf16 hi + bf16 lo) ----------
__global__ void conv_x_split(const float* __restrict__ x, u16* __restrict__ oh,
                             u16* __restrict__ ol) {
  size_t i = (size_t)blockIdx.x * 256 + threadIdx.x;
  f32x4 v = *(const f32x4*)(x + i * 4);
  u16x4v h, l;
#pragma unroll
  for (int j = 0; j < 4; ++j) {
    h[j] = f2bf(v[j]);
    l[j] = f2bf(v[j] - bf2f(h[j]));
  }
  *(u16x4v*)(oh + i * 4) = h;
  *(u16x4v*)(ol + i * 4) = l;
}

// ---------- transpose: W[K][N] f32 -> Wt[N][K] bf16 ----------
__global__ void conv_wT(const float* __restrict__ W, u16* __restrict__ Wt,
                        int Kd, int Nd) {
  __shared__ float t[32][33];
  int n0 = blockIdx.x * 32, k0 = blockIdx.y * 32;
  int c = threadIdx.x & 31, r8 = threadIdx.x >> 5;
#pragma unroll
  for (int rr = 0; rr < 32; rr += 8)
    t[r8 + rr][c] = W[(size_t)(k0 + r8 + rr) * Nd + n0 + c];
  __syncthreads();
#pragma unroll
  for (int rr = 0; rr < 32; rr += 8)
    Wt[(size_t)(n0 + r8 + rr) * Kd + k0 + c] = f2bf(t[c][r8 + rr]);
}

// ---------- combined QKV projection GEMM: C = Ah@Bh + Al@Bh ----------
__global__ void __launch_bounds__(256, 2)
gemmQKV(const u16* __restrict__ Ah, const u16* __restrict__ Al,
        const u16* __restrict__ Bt, u16* __restrict__ Qb,
        u16* __restrict__ Kb, u16* __restrict__ Vb, int M, int N, int K) {
  __shared__ u16 AsH[128][64];
  __shared__ u16 AsL[128][64];
  __shared__ u16 BsH[128][64];
  const int tid = threadIdx.x;
  const int lane = tid & 63, wave = tid >> 6;
  const int wr = wave >> 1, wc = wave & 1;
  const int lr = lane & 15, lg = lane >> 4;
  const int bm = blockIdx.y * 128, bn = blockIdx.x * 128;
  const int lrow = lane >> 3;
  const int lcol8 = (lane & 7) * 8;

  f32x4 acc[4][4];
#pragma unroll
  for (int m = 0; m < 4; ++m)
#pragma unroll
    for (int n = 0; n < 4; ++n) acc[m][n] = (f32x4){0.f, 0.f, 0.f, 0.f};

  for (int k0 = 0; k0 < K; k0 += 64) {
    __syncthreads();
#pragma unroll
    for (int c = 0; c < 4; ++c) {
      int r0 = wave * 32 + c * 8;
      size_t arow = (size_t)(bm + r0 + lrow) * K + k0 + lcol8;
      size_t brow = (size_t)(bn + r0 + lrow) * K + k0 + lcol8;
      gload16(Ah + arow, &AsH[r0][0]);
      gload16(Al + arow, &AsL[r0][0]);
      gload16(Bt + brow, &BsH[r0][0]);
    }
    __syncthreads();
#pragma unroll
    for (int kk = 0; kk < 2; ++kk) {
      bf16x8 afh[4], afl[4], bfh[4];
#pragma unroll
      for (int m = 0; m < 4; ++m) {
        afh[m] = *(const bf16x8*)&AsH[wr * 64 + m * 16 + lr][kk * 32 + lg * 8];
        afl[m] = *(const bf16x8*)&AsL[wr * 64 + m * 16 + lr][kk * 32 + lg * 8];
      }
#pragma unroll
      for (int n = 0; n < 4; ++n)
        bfh[n] = *(const bf16x8*)&BsH[wc * 64 + n * 16 + lr][kk * 32 + lg * 8];
#pragma unroll
      for (int m = 0; m < 4; ++m)
#pragma unroll
        for (int n = 0; n < 4; ++n) {
          acc[m][n] = __builtin_amdgcn_mfma_f32_16x16x32_bf16(afh[m], bfh[n],
                                                              acc[m][n], 0, 0, 0);
          acc[m][n] = __builtin_amdgcn_mfma_f32_16x16x32_bf16(afl[m], bfh[n],
                                                              acc[m][n], 0, 0, 0);
        }
    }
  }

  const int sel = bn >> 10;  // 0=Q, 1=K, 2=V
  u16* __restrict__ dst = sel == 0 ? Qb : (sel == 1 ? Kb : Vb);
  if (sel < 2) {  // fp32 RoPE on rotary dims
    float inv = __expf(-(float)lr * 0.5756462732485115f);
#pragma unroll
    for (int m = 0; m < 4; ++m) {
#pragma unroll
      for (int r = 0; r < 4; ++r) {
        int row = bm + wr * 64 + m * 16 + 4 * lg + r;
        int s = row & (SEQ - 1);
        float ang = (float)s * inv;
        float sn, cs;
        __sincosf(ang, &sn, &cs);
        float x1 = acc[m][0][r], x2 = acc[m][1][r];
        acc[m][0][r] = x1 * cs - x2 * sn;
        acc[m][1][r] = x2 * cs + x1 * sn;
      }
    }
  }

#pragma unroll
  for (int m = 0; m < 4; ++m) {
#pragma unroll
    for (int n = 0; n < 4; ++n) {
#pragma unroll
      for (int r = 0; r < 4; ++r) {
        int row = bm + wr * 64 + m * 16 + 4 * lg + r;
        int col = bn + wc * 64 + n * 16 + lr;
        int b = row >> 11, s = row & 2047;
        int h = (col >> 6) & 15, d = col & 63;
        dst[(((size_t)(b * NH + h)) * SEQ + s) * HD + d] = f2bf(acc[m][n][r]);
      }
    }
  }
}

// ---------- output projection GEMM, 128x64 tiles ----------
__global__ void __launch_bounds__(256, 2)
gemm1(const u16* __restrict__ A, const u16* __restrict__ Bt,
      float* __restrict__ CF, int M, int N, int K) {
  __shared__ u16 As[128][64];
  __shared__ u16 Bs[64][64];
  const int tid = threadIdx.x;
  const int lane = tid & 63, wave = tid >> 6;
  const int wr = wave >> 1, wc = wave & 1;
  const int lr = lane & 15, lg = lane >> 4;
  const int bm = blockIdx.y * 128, bn = blockIdx.x * 64;
  const int lrow = lane >> 3;
  const int lcol8 = (lane & 7) * 8;

  f32x4 acc[4][2];
#pragma unroll
  for (int m = 0; m < 4; ++m)
#pragma unroll
    for (int n = 0; n < 2; ++n) acc[m][n] = (f32x4){0.f, 0.f, 0.f, 0.f};

  for (int k0 = 0; k0 < K; k0 += 64) {
    __syncthreads();
#pragma unroll
    for (int c = 0; c < 4; ++c) {
      int r0 = wave * 32 + c * 8;
      gload16(A + (size_t)(bm + r0 + lrow) * K + k0 + lcol8, &As[r0][0]);
    }
#pragma unroll
    for (int c = 0; c < 2; ++c) {
      int r0 = wave * 16 + c * 8;
      gload16(Bt + (size_t)(bn + r0 + lrow) * K + k0 + lcol8, &Bs[r0][0]);
    }
    __syncthreads();
#pragma unroll
    for (int kk = 0; kk < 2; ++kk) {
      bf16x8 af[4], bfr[2];
#pragma unroll
      for (int m = 0; m < 4; ++m)
        af[m] = *(const bf16x8*)&As[wr * 64 + m * 16 + lr][kk * 32 + lg * 8];
#pragma unroll
      for (int n = 0; n < 2; ++n)
        bfr[n] = *(const bf16x8*)&Bs[wc * 32 + n * 16 + lr][kk * 32 + lg * 8];
#pragma unroll
      for (int m = 0; m < 4; ++m)
#pragma unroll
        for (int n = 0; n < 2; ++n)
          acc[m][n] = __builtin_amdgcn_mfma_f32_16x16x32_bf16(af[m], bfr[n],
                                                              acc[m][n], 0, 0, 0);
    }
  }

#pragma unroll
  for (int m = 0; m < 4; ++m)
#pragma unroll
    for (int n = 0; n < 2; ++n)
#pragma unroll
      for (int r = 0; r < 4; ++r) {
        int row = bm + wr * 64 + m * 16 + 4 * lg + r;
        int col = bn + wc * 32 + n * 16 + lr;
        CF[(size_t)row * N + col] = acc[m][n][r];
      }
}

// ---------- flash attention: 32x32 swapped-QK^T, in-register softmax --------
// Grid (8, 32), 512 threads (8 waves). qtiles of 128: qtA = bx, qtB = 15-bx
// (uniform 17 kv-tile iterations/block). Waves: group g = wave>>2 takes KV half
// g of each qt; wave w4 = wave&3 owns q-rows [qt*128 + w4*32, +32).
// Swapped: S^T = mfma32(K, Q) -> lane holds 32 P-vals for ONE q-row; softmax
// fully in-register (1 shfl per reduce); P->PV B-frag via pack + shfl_xor(32).
__global__ void __launch_bounds__(512, 1)
attn_kernel(const u16* __restrict__ Q, const u16* __restrict__ K,
            const u16* __restrict__ V, float* __restrict__ Op0,
            float* __restrict__ Op1, float* __restrict__ ml) {
  __shared__ u16 Ks[2][64][72];
  __shared__ u16 Vt[2][64][72];  // Vt[g][d][kv]
  const int tid = threadIdx.x, lane = tid & 63, wave = tid >> 6;
  const int g = wave >> 2, w4 = wave & 3;
  const int hi = lane >> 5, l31 = lane & 31;
  const int tid_g = w4 * 64 + lane;  // 0..255 within group
  const int bx = blockIdx.x, bh = blockIdx.y;
  const size_t kvbase = (size_t)bh * SEQ * HD;
  const int HS = 32 * SEQ;
  // staging coords
  const int kr0 = tid_g >> 3, kc0 = (tid_g & 7) * 8;   // K row (x2), col chunk
  const int vr = tid_g & 63;                            // V row
  const int vc0A = (tid_g >> 6) * 8, vc0B = vc0A + 32;  // V col chunks

  u16x8v kreg0, kreg1, vreg0, vreg1;
  float* __restrict__ Opart = g ? Op1 : Op0;

#pragma unroll 1
  for (int phase = 0; phase < 2; ++phase) {
    const int qt = phase ? 15 - bx : bx;
    const int nper = qt + 1;          // kv tiles per group
    const int ktbegin = g * nper;
    const int qrow = qt * 128 + w4 * 32 + l31;

    // Q fragments: qf[kk] = Q[qrow][16kk + 8hi .. +7]
    const u16* qp = Q + kvbase + (size_t)qrow * HD + 8 * hi;
    bf16x8 qf0 = *(const bf16x8*)(qp);
    bf16x8 qf1 = *(const bf16x8*)(qp + 16);
    bf16x8 qf2 = *(const bf16x8*)(qp + 32);
    bf16x8 qf3 = *(const bf16x8*)(qp + 48);

    f32x16 o0 = {0.f}, o1 = {0.f};
    float m = -1e30f, l = 0.f;

    // prologue prefetch
    {
      const u16* kp = K + kvbase + (size_t)(ktbegin * 64) * HD;
      const u16* vp = V + kvbase + (size_t)(ktbegin * 64) * HD;
      kreg0 = *(const u16x8v*)(kp + (size_t)kr0 * HD + kc0);
      kreg1 = *(const u16x8v*)(kp + (size_t)(kr0 + 32) * HD + kc0);
      vreg0 = *(const u16x8v*)(vp + (size_t)vr * HD + vc0A);
      vreg1 = *(const u16x8v*)(vp + (size_t)vr * HD + vc0B);
    }

#pragma unroll 1
    for (int i = 0; i < nper; ++i) {
      const int kt = ktbegin + i;
      __syncthreads();
      *(u16x8v*)&Ks[g][kr0][kc0] = kreg0;
      *(u16x8v*)&Ks[g][kr0 + 32][kc0] = kreg1;
#pragma unroll
      for (int j = 0; j < 8; ++j) Vt[g][vc0A + j][vr] = vreg0[j];
#pragma unroll
      for (int j = 0; j < 8; ++j) Vt[g][vc0B + j][vr] = vreg1[j];
      __syncthreads();
      if (i + 1 < nper) {
        const u16* kp = K + kvbase + (size_t)((kt + 1) * 64) * HD;
        const u16* vp = V + kvbase + (size_t)((kt + 1) * 64) * HD;
        kreg0 = *(const u16x8v*)(kp + (size_t)kr0 * HD + kc0);
        kreg1 = *(const u16x8v*)(kp + (size_t)(kr0 + 32) * HD + kc0);
        vreg0 = *(const u16x8v*)(vp + (size_t)vr * HD + vc0A);
        vreg1 = *(const u16x8v*)(vp + (size_t)vr * HD + vc0B);
      }

      // QK^T: S^T[kv][q], lane: q = l31, kv rows (reg&3)+8*(reg>>2)+4hi (+32)
      f32x16 s0 = {0.f}, s1 = {0.f};
      __builtin_amdgcn_s_setprio(1);
#pragma unroll
      for (int kk = 0; kk < 4; ++kk) {
        bf16x8 qk = kk == 0 ? qf0 : (kk == 1 ? qf1 : (kk == 2 ? qf2 : qf3));
        bf16x8 af0 = *(const bf16x8*)&Ks[g][l31][16 * kk + 8 * hi];
        bf16x8 af1 = *(const bf16x8*)&Ks[g][32 + l31][16 * kk + 8 * hi];
        s0 = __builtin_amdgcn_mfma_f32_32x32x16_bf16(af0, qk, s0, 0, 0, 0);
        s1 = __builtin_amdgcn_mfma_f32_32x32x16_bf16(af1, qk, s1, 0, 0, 0);
      }
      __builtin_amdgcn_s_setprio(0);
      s0 *= 0.125f;
      s1 *= 0.125f;

      if (kt >= 2 * qt) {  // diagonal tiles: mask kv > q
#pragma unroll
        for (int r = 0; r < 16; ++r) {
          int rowi = (r & 3) + 8 * (r >> 2) + 4 * hi;
          if (kt * 64 + rowi > qrow) s0[r] = -1e30f;
          if (kt * 64 + 32 + rowi > qrow) s1[r] = -1e30f;
        }
      }

      // row max: serial over 32 regs + partner half
      float mx = s0[0];
#pragma unroll
      for (int r = 1; r < 16; ++r) mx = fmaxf(mx, s0[r]);
#pragma unroll
      for (int r = 0; r < 16; ++r) mx = fmaxf(mx, s1[r]);
      mx = fmaxf(mx, __shfl_xor(mx, 32));

      bool defer = __all(mx - m <= 8.f);
      if (!defer) {
        float mn = fmaxf(m, mx);
        float fac = __expf(m - mn);
        m = mn;
        l *= fac;
        o0 *= fac;
        o1 *= fac;
      }
      // P = exp(S - m), row sum
      float rsum = 0.f;
#pragma unroll
      for (int r = 0; r < 16; ++r) {
        s0[r] = __expf(s0[r] - m);
        rsum += s0[r];
      }
#pragma unroll
      for (int r = 0; r < 16; ++r) {
        s1[r] = __expf(s1[r] - m);
        rsum += s1[r];
      }
      rsum += __shfl_xor(rsum, 32);
      l += rsum;

      // pack bf16 pairs: P0[kvs][gg]=(v[4gg],v[4gg+1]), P1=(v[4gg+2],v[4gg+3])
      u32 P0a[4], P1a[4], P0b[4], P1b[4];
#pragma unroll
      for (int gg = 0; gg < 4; ++gg) {
        P0a[gg] = pk2(s0[4 * gg], s0[4 * gg + 1]);
        P1a[gg] = pk2(s0[4 * gg + 2], s0[4 * gg + 3]);
        P0b[gg] = pk2(s1[4 * gg], s1[4 * gg + 1]);
        P1b[gg] = pk2(s1[4 * gg + 2], s1[4 * gg + 3]);
      }

      // PV: O^T += V^T @ P^T, 4 k-chunks of 16 kv
      __builtin_amdgcn_s_setprio(1);
#pragma unroll
      for (int c = 0; c < 4; ++c) {
        const int gA = 2 * (c & 1);
        u32 p0lo, p0hi, p1lo, p1hi;
        if (c < 2) {  // kvsub 0
          p0lo = P0a[gA];
          p0hi = P0a[gA + 1];
          p1lo = P1a[gA];
          p1hi = P1a[gA + 1];
        } else {  // kvsub 1
          p0lo = P0b[gA];
          p0hi = P0b[gA + 1];
          p1lo = P1b[gA];
          p1hi = P1b[gA + 1];
        }
        u32 send0 = hi ? p0lo : p0hi;
        u32 send1 = hi ? p1lo : p1hi;
        u32 recv0 = (u32)__shfl_xor((int)send0, 32);
        u32 recv1 = (u32)__shfl_xor((int)send1, 32);
        u32 own0 = hi ? p0hi : p0lo;
        u32 own1 = hi ? p1hi : p1lo;
        u32x4 bw;
        bw[0] = hi ? recv0 : own0;
        bw[1] = hi ? recv1 : own1;
        bw[2] = hi ? own0 : recv0;
        bw[3] = hi ? own1 : recv1;
        bf16x8 bfrag = __builtin_bit_cast(bf16x8, bw);
        bf16x8 av0 = *(const bf16x8*)&Vt[g][l31][16 * c + 8 * hi];
        bf16x8 av1 = *(const bf16x8*)&Vt[g][32 + l31][16 * c + 8 * hi];
        o0 = __builtin_amdgcn_mfma_f32_32x32x16_bf16(av0, bfrag, o0, 0, 0, 0);
        o1 = __builtin_amdgcn_mfma_f32_32x32x16_bf16(av1, bfrag, o1, 0, 0, 0);
      }
      __builtin_amdgcn_s_setprio(0);
    }

    // epilogue: premultiplied O^T partial -> Opart[bh][s][d] (f32), m/l
    {
      size_t base = ((size_t)bh * SEQ + qrow) * HD;
#pragma unroll
      for (int gg = 0; gg < 4; ++gg) {
        f32x4 v0 = {o0[4 * gg], o0[4 * gg + 1], o0[4 * gg + 2], o0[4 * gg + 3]};
        f32x4 v1 = {o1[4 * gg], o1[4 * gg + 1], o1[4 * gg + 2], o1[4 * gg + 3]};
        *(f32x4*)(Opart + base + 8 * gg + 4 * hi) = v0;
        *(f32x4*)(Opart + base + 32 + 8 * gg + 4 * hi) = v1;
      }
      if (hi == 0) {
        ml[g * HS + bh * SEQ + qrow] = m;
        ml[2 * HS + g * HS + bh * SEQ + qrow] = l;
      }
    }
    __syncthreads();  // protect LDS before next phase staging
  }
}

// ---------- merge the two KV-half partials, write bf16 O [b,s,h*64+d] -------
__global__ void merge_kernel(const float* __restrict__ Op0,
                             const float* __restrict__ Op1,
                             const float* __restrict__ ml,
                             u16* __restrict__ O) {
  int i = blockIdx.x * 256 + threadIdx.x;
  int row = i >> 4;  // bh*SEQ + s
  int d0 = (i & 15) * 4;
  size_t base = (size_t)row * 64 + d0;
  f32x4 o1 = *(const f32x4*)(Op0 + base);
  f32x4 o2 = *(const f32x4*)(Op1 + base);
  const int HS = 32 * SEQ;
  float m1 = ml[row], m2 = ml[HS + row];
  float l1 = ml[2 * HS + row], l2 = ml[3 * HS + row];
  float M = fmaxf(m1, m2);
  float w1 = __expf(m1 - M), w2 = __expf(m2 - M);
  float inv = 1.0f / (l1 * w1 + l2 * w2);
  int bh = row >> 11, s = row & 2047;
  int b = bh >> 4, h = bh & 15;
  u16x4v rr;
#pragma unroll
  for (int j = 0; j < 4; ++j) rr[j] = f2bf((o1[j] * w1 + o2[j] * w2) * inv);
  *(u16x4v*)(O + ((size_t)(b * SEQ + s)) * DIMM + h * HD + d0) = rr;
}

extern "C" void kernel_launch(void* const* d_in, const int* in_sizes, int n_in,
                              void* d_out, int out_size, void* d_ws, size_t ws_size,
                              hipStream_t stream) {
  const float* x = (const float*)d_in[0];
  const float* wq = (const float*)d_in[1];
  const float* wkv = (const float*)d_in[2];
  const float* wout = (const float*)d_in[3];
  float* out = (float*)d_out;

  u16* ws = (u16*)d_ws;
  const size_t M1 = (size_t)1024 * 1024;
  u16* xh = ws;                    // 4M u16
  u16* xl = xh + 4 * M1;           // 4M
  u16* wqTh = xl + 4 * M1;         // 1M  (wkvTh contiguous -> B[3072][1024])
  u16* wkvTh = wqTh + M1;          // 2M
  u16* Qb = wkvTh + 2 * M1;        // 4M
  u16* Kb = Qb + 4 * M1;           // 4M
  u16* Vb = Kb + 4 * M1;           // 4M
  // overlays:
  float* Op0 = out;                // d_out as scratch: 16MB
  float* Op1 = (float*)xh;         // xh+xl = 16MB
  float* mlbuf = (float*)wqTh;     // 1MB need; 2MB slab
  u16* Ob = Qb;                    // 8MB need; Qb dead after attn
  u16* woutT = Kb;                 // 2MB need; Kb dead after attn

  conv_x_split<<<4096, 256, 0, stream>>>(x, xh, xl);
  conv_wT<<<dim3(32, 32), 256, 0, stream>>>(wq, wqTh, 1024, 1024);
  conv_wT<<<dim3(64, 32), 256, 0, stream>>>(wkv, wkvTh, 1024, 2048);

  gemmQKV<<<dim3(24, 32), 256, 0, stream>>>(xh, xl, wqTh, Qb, Kb, Vb,
                                            4096, 3072, 1024);

  attn_kernel<<<dim3(8, 32), 512, 0, stream>>>(Qb, Kb, Vb, Op0, Op1, mlbuf);
  merge_kernel<<<4096, 256, 0, stream>>>(Op0, Op1, mlbuf, Ob);

  conv_wT<<<dim3(32, 32), 256, 0, stream>>>(wout, woutT, 1024, 1024);
  gemm1<<<dim3(16, 32), 256, 0, stream>>>(Ob, woutT, out, 4096, 1024, 1024);
}

// Round 13
// 129.658 us; speedup vs baseline: 2.2385x; 1.1767x over previous
//
#include <hip/hip_runtime.h>

typedef unsigned short u16;
typedef unsigned int u32;
typedef __bf16 bf16x8 __attribute__((ext_vector_type(8)));
typedef unsigned short u16x8v __attribute__((ext_vector_type(8)));
typedef unsigned short u16x4v __attribute__((ext_vector_type(4)));
typedef unsigned int u32x4 __attribute__((ext_vector_type(4)));
typedef float f32x4 __attribute__((ext_vector_type(4)));
typedef float f32x16 __attribute__((ext_vector_type(16)));

#define SEQ 2048
#define NH 16
#define HD 64
#define DIMM 1024

__device__ __forceinline__ u16 f2bf(float f) {
  unsigned u = __builtin_bit_cast(unsigned, f);
  u += 0x7fffu + ((u >> 16) & 1u);
  return (u16)(u >> 16);
}
__device__ __forceinline__ float bf2f(u16 b) {
  return __builtin_bit_cast(float, ((unsigned)b) << 16);
}
__device__ __forceinline__ u32 pk2(float a, float b) {
  return (u32)f2bf(a) | ((u32)f2bf(b) << 16);
}

// async global->LDS, 16B per lane; LDS dest = wave-uniform base + lane*16
__device__ __forceinline__ void gload16(const u16* g, u16* l) {
  __builtin_amdgcn_global_load_lds(
      (const __attribute__((address_space(1))) unsigned int*)g,
      (__attribute__((address_space(3))) unsigned int*)l, 16, 0, 0);
}

// ---------- convert x (f32 -> bf16) ----------
__global__ void conv_x(const float* __restrict__ x, u16* __restrict__ oh) {
  size_t i = (size_t)blockIdx.x * 256 + threadIdx.x;
  f32x4 v = *(const f32x4*)(x + i * 4);
  u16x4v h;
#pragma unroll
  for (int j = 0; j < 4; ++j) h[j] = f2bf(v[j]);
  *(u16x4v*)(oh + i * 4) = h;
}

// ---------- transpose: W[K][N] f32 -> Wt[N][K] bf16 ----------
__global__ void conv_wT(const float* __restrict__ W, u16* __restrict__ Wt,
                        int Kd, int Nd) {
  __shared__ float t[32][33];
  int n0 = blockIdx.x * 32, k0 = blockIdx.y * 32;
  int c = threadIdx.x & 31, r8 = threadIdx.x >> 5;
#pragma unroll
  for (int rr = 0; rr < 32; rr += 8)
    t[r8 + rr][c] = W[(size_t)(k0 + r8 + rr) * Nd + n0 + c];
  __syncthreads();
#pragma unroll
  for (int rr = 0; rr < 32; rr += 8)
    Wt[(size_t)(n0 + r8 + rr) * Kd + k0 + c] = f2bf(t[c][r8 + rr]);
}

// ---------- combined QKV projection GEMM (single-term bf16) ----------
// B = [wqT | wkvT] rows: col<1024 -> Q (rope), 1024..2047 -> K (rope), else V.
__global__ void __launch_bounds__(256, 2)
gemmQKV(const u16* __restrict__ Ah, const u16* __restrict__ Bt,
        u16* __restrict__ Qb, u16* __restrict__ Kb, u16* __restrict__ Vb,
        int M, int N, int K) {
  __shared__ u16 AsH[128][64];
  __shared__ u16 BsH[128][64];
  const int tid = threadIdx.x;
  const int lane = tid & 63, wave = tid >> 6;
  const int wr = wave >> 1, wc = wave & 1;
  const int lr = lane & 15, lg = lane >> 4;
  const int bm = blockIdx.y * 128, bn = blockIdx.x * 128;
  const int lrow = lane >> 3;
  const int lcol8 = (lane & 7) * 8;

  f32x4 acc[4][4];
#pragma unroll
  for (int m = 0; m < 4; ++m)
#pragma unroll
    for (int n = 0; n < 4; ++n) acc[m][n] = (f32x4){0.f, 0.f, 0.f, 0.f};

  for (int k0 = 0; k0 < K; k0 += 64) {
    __syncthreads();
#pragma unroll
    for (int c = 0; c < 4; ++c) {
      int r0 = wave * 32 + c * 8;
      size_t arow = (size_t)(bm + r0 + lrow) * K + k0 + lcol8;
      size_t brow = (size_t)(bn + r0 + lrow) * K + k0 + lcol8;
      gload16(Ah + arow, &AsH[r0][0]);
      gload16(Bt + brow, &BsH[r0][0]);
    }
    __syncthreads();
#pragma unroll
    for (int kk = 0; kk < 2; ++kk) {
      bf16x8 afh[4], bfh[4];
#pragma unroll
      for (int m = 0; m < 4; ++m)
        afh[m] = *(const bf16x8*)&AsH[wr * 64 + m * 16 + lr][kk * 32 + lg * 8];
#pragma unroll
      for (int n = 0; n < 4; ++n)
        bfh[n] = *(const bf16x8*)&BsH[wc * 64 + n * 16 + lr][kk * 32 + lg * 8];
#pragma unroll
      for (int m = 0; m < 4; ++m)
#pragma unroll
        for (int n = 0; n < 4; ++n)
          acc[m][n] = __builtin_amdgcn_mfma_f32_16x16x32_bf16(afh[m], bfh[n],
                                                              acc[m][n], 0, 0, 0);
    }
  }

  const int sel = bn >> 10;  // 0=Q, 1=K, 2=V
  u16* __restrict__ dst = sel == 0 ? Qb : (sel == 1 ? Kb : Vb);
  if (sel < 2) {  // fp32 RoPE on rotary dims
    float inv = __expf(-(float)lr * 0.5756462732485115f);
#pragma unroll
    for (int m = 0; m < 4; ++m) {
#pragma unroll
      for (int r = 0; r < 4; ++r) {
        int row = bm + wr * 64 + m * 16 + 4 * lg + r;
        int s = row & (SEQ - 1);
        float ang = (float)s * inv;
        float sn, cs;
        __sincosf(ang, &sn, &cs);
        float x1 = acc[m][0][r], x2 = acc[m][1][r];
        acc[m][0][r] = x1 * cs - x2 * sn;
        acc[m][1][r] = x2 * cs + x1 * sn;
      }
    }
  }

#pragma unroll
  for (int m = 0; m < 4; ++m) {
#pragma unroll
    for (int n = 0; n < 4; ++n) {
#pragma unroll
      for (int r = 0; r < 4; ++r) {
        int row = bm + wr * 64 + m * 16 + 4 * lg + r;
        int col = bn + wc * 64 + n * 16 + lr;
        int b = row >> 11, s = row & 2047;
        int h = (col >> 6) & 15, d = col & 63;
        dst[(((size_t)(b * NH + h)) * SEQ + s) * HD + d] = f2bf(acc[m][n][r]);
      }
    }
  }
}

// ---------- output projection GEMM, 128x64 tiles ----------
__global__ void __launch_bounds__(256, 2)
gemm1(const u16* __restrict__ A, const u16* __restrict__ Bt,
      float* __restrict__ CF, int M, int N, int K) {
  __shared__ u16 As[128][64];
  __shared__ u16 Bs[64][64];
  const int tid = threadIdx.x;
  const int lane = tid & 63, wave = tid >> 6;
  const int wr = wave >> 1, wc = wave & 1;
  const int lr = lane & 15, lg = lane >> 4;
  const int bm = blockIdx.y * 128, bn = blockIdx.x * 64;
  const int lrow = lane >> 3;
  const int lcol8 = (lane & 7) * 8;

  f32x4 acc[4][2];
#pragma unroll
  for (int m = 0; m < 4; ++m)
#pragma unroll
    for (int n = 0; n < 2; ++n) acc[m][n] = (f32x4){0.f, 0.f, 0.f, 0.f};

  for (int k0 = 0; k0 < K; k0 += 64) {
    __syncthreads();
#pragma unroll
    for (int c = 0; c < 4; ++c) {
      int r0 = wave * 32 + c * 8;
      gload16(A + (size_t)(bm + r0 + lrow) * K + k0 + lcol8, &As[r0][0]);
    }
#pragma unroll
    for (int c = 0; c < 2; ++c) {
      int r0 = wave * 16 + c * 8;
      gload16(Bt + (size_t)(bn + r0 + lrow) * K + k0 + lcol8, &Bs[r0][0]);
    }
    __syncthreads();
#pragma unroll
    for (int kk = 0; kk < 2; ++kk) {
      bf16x8 af[4], bfr[2];
#pragma unroll
      for (int m = 0; m < 4; ++m)
        af[m] = *(const bf16x8*)&As[wr * 64 + m * 16 + lr][kk * 32 + lg * 8];
#pragma unroll
      for (int n = 0; n < 2; ++n)
        bfr[n] = *(const bf16x8*)&Bs[wc * 32 + n * 16 + lr][kk * 32 + lg * 8];
#pragma unroll
      for (int m = 0; m < 4; ++m)
#pragma unroll
        for (int n = 0; n < 2; ++n)
          acc[m][n] = __builtin_amdgcn_mfma_f32_16x16x32_bf16(af[m], bfr[n],
                                                              acc[m][n], 0, 0, 0);
    }
  }

#pragma unroll
  for (int m = 0; m < 4; ++m)
#pragma unroll
    for (int n = 0; n < 2; ++n)
#pragma unroll
      for (int r = 0; r < 4; ++r) {
        int row = bm + wr * 64 + m * 16 + 4 * lg + r;
        int col = bn + wc * 32 + n * 16 + lr;
        CF[(size_t)row * N + col] = acc[m][n][r];
      }
}

// ---------- flash attention: 32x32 swapped-QK^T, in-register softmax --------
__global__ void __launch_bounds__(512, 1)
attn_kernel(const u16* __restrict__ Q, const u16* __restrict__ K,
            const u16* __restrict__ V, float* __restrict__ Op0,
            float* __restrict__ Op1, float* __restrict__ ml) {
  __shared__ u16 Ks[2][64][72];
  __shared__ u16 Vt[2][64][72];  // Vt[g][d][kv]
  const int tid = threadIdx.x, lane = tid & 63, wave = tid >> 6;
  const int g = wave >> 2, w4 = wave & 3;
  const int hi = lane >> 5, l31 = lane & 31;
  const int tid_g = w4 * 64 + lane;  // 0..255 within group
  const int bx = blockIdx.x, bh = blockIdx.y;
  const size_t kvbase = (size_t)bh * SEQ * HD;
  const int HS = 32 * SEQ;
  const int kr0 = tid_g >> 3, kc0 = (tid_g & 7) * 8;
  const int vr = tid_g & 63;
  const int vc0A = (tid_g >> 6) * 8, vc0B = vc0A + 32;

  u16x8v kreg0, kreg1, vreg0, vreg1;
  float* __restrict__ Opart = g ? Op1 : Op0;

#pragma unroll 1
  for (int phase = 0; phase < 2; ++phase) {
    const int qt = phase ? 15 - bx : bx;
    const int nper = qt + 1;
    const int ktbegin = g * nper;
    const int qrow = qt * 128 + w4 * 32 + l31;

    const u16* qp = Q + kvbase + (size_t)qrow * HD + 8 * hi;
    bf16x8 qf0 = *(const bf16x8*)(qp);
    bf16x8 qf1 = *(const bf16x8*)(qp + 16);
    bf16x8 qf2 = *(const bf16x8*)(qp + 32);
    bf16x8 qf3 = *(const bf16x8*)(qp + 48);

    f32x16 o0 = {0.f}, o1 = {0.f};
    float m = -1e30f, l = 0.f;

    {
      const u16* kp = K + kvbase + (size_t)(ktbegin * 64) * HD;
      const u16* vp = V + kvbase + (size_t)(ktbegin * 64) * HD;
      kreg0 = *(const u16x8v*)(kp + (size_t)kr0 * HD + kc0);
      kreg1 = *(const u16x8v*)(kp + (size_t)(kr0 + 32) * HD + kc0);
      vreg0 = *(const u16x8v*)(vp + (size_t)vr * HD + vc0A);
      vreg1 = *(const u16x8v*)(vp + (size_t)vr * HD + vc0B);
    }

#pragma unroll 1
    for (int i = 0; i < nper; ++i) {
      const int kt = ktbegin + i;
      __syncthreads();
      *(u16x8v*)&Ks[g][kr0][kc0] = kreg0;
      *(u16x8v*)&Ks[g][kr0 + 32][kc0] = kreg1;
#pragma unroll
      for (int j = 0; j < 8; ++j) Vt[g][vc0A + j][vr] = vreg0[j];
#pragma unroll
      for (int j = 0; j < 8; ++j) Vt[g][vc0B + j][vr] = vreg1[j];
      __syncthreads();
      if (i + 1 < nper) {
        const u16* kp = K + kvbase + (size_t)((kt + 1) * 64) * HD;
        const u16* vp = V + kvbase + (size_t)((kt + 1) * 64) * HD;
        kreg0 = *(const u16x8v*)(kp + (size_t)kr0 * HD + kc0);
        kreg1 = *(const u16x8v*)(kp + (size_t)(kr0 + 32) * HD + kc0);
        vreg0 = *(const u16x8v*)(vp + (size_t)vr * HD + vc0A);
        vreg1 = *(const u16x8v*)(vp + (size_t)vr * HD + vc0B);
      }

      f32x16 s0 = {0.f}, s1 = {0.f};
      __builtin_amdgcn_s_setprio(1);
#pragma unroll
      for (int kk = 0; kk < 4; ++kk) {
        bf16x8 qk = kk == 0 ? qf0 : (kk == 1 ? qf1 : (kk == 2 ? qf2 : qf3));
        bf16x8 af0 = *(const bf16x8*)&Ks[g][l31][16 * kk + 8 * hi];
        bf16x8 af1 = *(const bf16x8*)&Ks[g][32 + l31][16 * kk + 8 * hi];
        s0 = __builtin_amdgcn_mfma_f32_32x32x16_bf16(af0, qk, s0, 0, 0, 0);
        s1 = __builtin_amdgcn_mfma_f32_32x32x16_bf16(af1, qk, s1, 0, 0, 0);
      }
      __builtin_amdgcn_s_setprio(0);
      s0 *= 0.125f;
      s1 *= 0.125f;

      if (kt >= 2 * qt) {
#pragma unroll
        for (int r = 0; r < 16; ++r) {
          int rowi = (r & 3) + 8 * (r >> 2) + 4 * hi;
          if (kt * 64 + rowi > qrow) s0[r] = -1e30f;
          if (kt * 64 + 32 + rowi > qrow) s1[r] = -1e30f;
        }
      }

      float mx = s0[0];
#pragma unroll
      for (int r = 1; r < 16; ++r) mx = fmaxf(mx, s0[r]);
#pragma unroll
      for (int r = 0; r < 16; ++r) mx = fmaxf(mx, s1[r]);
      mx = fmaxf(mx, __shfl_xor(mx, 32));

      bool defer = __all(mx - m <= 8.f);
      if (!defer) {
        float mn = fmaxf(m, mx);
        float fac = __expf(m - mn);
        m = mn;
        l *= fac;
        o0 *= fac;
        o1 *= fac;
      }
      float rsum = 0.f;
#pragma unroll
      for (int r = 0; r < 16; ++r) {
        s0[r] = __expf(s0[r] - m);
        rsum += s0[r];
      }
#pragma unroll
      for (int r = 0; r < 16; ++r) {
        s1[r] = __expf(s1[r] - m);
        rsum += s1[r];
      }
      rsum += __shfl_xor(rsum, 32);
      l += rsum;

      u32 P0a[4], P1a[4], P0b[4], P1b[4];
#pragma unroll
      for (int gg = 0; gg < 4; ++gg) {
        P0a[gg] = pk2(s0[4 * gg], s0[4 * gg + 1]);
        P1a[gg] = pk2(s0[4 * gg + 2], s0[4 * gg + 3]);
        P0b[gg] = pk2(s1[4 * gg], s1[4 * gg + 1]);
        P1b[gg] = pk2(s1[4 * gg + 2], s1[4 * gg + 3]);
      }

      __builtin_amdgcn_s_setprio(1);
#pragma unroll
      for (int c = 0; c < 4; ++c) {
        const int gA = 2 * (c & 1);
        u32 p0lo, p0hi, p1lo, p1hi;
        if (c < 2) {
          p0lo = P0a[gA];
          p0hi = P0a[gA + 1];
          p1lo = P1a[gA];
          p1hi = P1a[gA + 1];
        } else {
          p0lo = P0b[gA];
          p0hi = P0b[gA + 1];
          p1lo = P1b[gA];
          p1hi = P1b[gA + 1];
        }
        u32 send0 = hi ? p0lo : p0hi;
        u32 send1 = hi ? p1lo : p1hi;
        u32 recv0 = (u32)__shfl_xor((int)send0, 32);
        u32 recv1 = (u32)__shfl_xor((int)send1, 32);
        u32 own0 = hi ? p0hi : p0lo;
        u32 own1 = hi ? p1hi : p1lo;
        u32x4 bw;
        bw[0] = hi ? recv0 : own0;
        bw[1] = hi ? recv1 : own1;
        bw[2] = hi ? own0 : recv0;
        bw[3] = hi ? own1 : recv1;
        bf16x8 bfrag = __builtin_bit_cast(bf16x8, bw);
        bf16x8 av0 = *(const bf16x8*)&Vt[g][l31][16 * c + 8 * hi];
        bf16x8 av1 = *(const bf16x8*)&Vt[g][32 + l31][16 * c + 8 * hi];
        o0 = __builtin_amdgcn_mfma_f32_32x32x16_bf16(av0, bfrag, o0, 0, 0, 0);
        o1 = __builtin_amdgcn_mfma_f32_32x32x16_bf16(av1, bfrag, o1, 0, 0, 0);
      }
      __builtin_amdgcn_s_setprio(0);
    }

    {
      size_t base = ((size_t)bh * SEQ + qrow) * HD;
#pragma unroll
      for (int gg = 0; gg < 4; ++gg) {
        f32x4 v0 = {o0[4 * gg], o0[4 * gg + 1], o0[4 * gg + 2], o0[4 * gg + 3]};
        f32x4 v1 = {o1[4 * gg], o1[4 * gg + 1], o1[4 * gg + 2], o1[4 * gg + 3]};
        *(f32x4*)(Opart + base + 8 * gg + 4 * hi) = v0;
        *(f32x4*)(Opart + base + 32 + 8 * gg + 4 * hi) = v1;
      }
      if (hi == 0) {
        ml[g * HS + bh * SEQ + qrow] = m;
        ml[2 * HS + g * HS + bh * SEQ + qrow] = l;
      }
    }
    __syncthreads();
  }
}

// ---------- merge the two KV-half partials, write bf16 O [b,s,h*64+d] -------
__global__ void merge_kernel(const float* __restrict__ Op0,
                             const float* __restrict__ Op1,
                             const float* __restrict__ ml,
                             u16* __restrict__ O) {
  int i = blockIdx.x * 256 + threadIdx.x;
  int row = i >> 4;  // bh*SEQ + s
  int d0 = (i & 15) * 4;
  size_t base = (size_t)row * 64 + d0;
  f32x4 o1 = *(const f32x4*)(Op0 + base);
  f32x4 o2 = *(const f32x4*)(Op1 + base);
  const int HS = 32 * SEQ;
  float m1 = ml[row], m2 = ml[HS + row];
  float l1 = ml[2 * HS + row], l2 = ml[3 * HS + row];
  float M = fmaxf(m1, m2);
  float w1 = __expf(m1 - M), w2 = __expf(m2 - M);
  float inv = 1.0f / (l1 * w1 + l2 * w2);
  int bh = row >> 11, s = row & 2047;
  int b = bh >> 4, h = bh & 15;
  u16x4v rr;
#pragma unroll
  for (int j = 0; j < 4; ++j) rr[j] = f2bf((o1[j] * w1 + o2[j] * w2) * inv);
  *(u16x4v*)(O + ((size_t)(b * SEQ + s)) * DIMM + h * HD + d0) = rr;
}

extern "C" void kernel_launch(void* const* d_in, const int* in_sizes, int n_in,
                              void* d_out, int out_size, void* d_ws, size_t ws_size,
                              hipStream_t stream) {
  const float* x = (const float*)d_in[0];
  const float* wq = (const float*)d_in[1];
  const float* wkv = (const float*)d_in[2];
  const float* wout = (const float*)d_in[3];
  float* out = (float*)d_out;

  u16* ws = (u16*)d_ws;
  const size_t M1 = (size_t)1024 * 1024;
  u16* xh = ws;                    // 4M u16 (xl slab kept reserved for Op1 overlay)
  u16* xl = xh + 4 * M1;           // 4M (unused as data; part of Op1 region)
  u16* wqTh = xl + 4 * M1;         // 1M  (wkvTh contiguous -> B[3072][1024])
  u16* wkvTh = wqTh + M1;          // 2M
  u16* Qb = wkvTh + 2 * M1;        // 4M
  u16* Kb = Qb + 4 * M1;           // 4M
  u16* Vb = Kb + 4 * M1;           // 4M
  // overlays:
  float* Op0 = out;                // d_out as scratch: 16MB
  float* Op1 = (float*)xh;         // xh+xl = 16MB (x dead after gemmQKV)
  float* mlbuf = (float*)wqTh;     // 1MB need; 2MB slab
  u16* Ob = Qb;                    // 8MB need; Qb dead after attn
  u16* woutT = Kb;                 // 2MB need; Kb dead after attn

  conv_x<<<4096, 256, 0, stream>>>(x, xh);
  conv_wT<<<dim3(32, 32), 256, 0, stream>>>(wq, wqTh, 1024, 1024);
  conv_wT<<<dim3(64, 32), 256, 0, stream>>>(wkv, wkvTh, 1024, 2048);

  gemmQKV<<<dim3(24, 32), 256, 0, stream>>>(xh, wqTh, Qb, Kb, Vb,
                                            4096, 3072, 1024);

  attn_kernel<<<dim3(8, 32), 512, 0, stream>>>(Qb, Kb, Vb, Op0, Op1, mlbuf);
  merge_kernel<<<4096, 256, 0, stream>>>(Op0, Op1, mlbuf, Ob);

  conv_wT<<<dim3(32, 32), 256, 0, stream>>>(wout, woutT, 1024, 1024);
  gemm1<<<dim3(16, 32), 256, 0, stream>>>(Ob, woutT, out, 4096, 1024, 1024);
}